// Round 9
// baseline (925.369 us; speedup 1.0000x reference)
//
#include <hip/hip_runtime.h>
#include <hip/hip_bf16.h>
#include <math.h>

#define NN 10000
#define NE 160000
#define NW (NE/16)     // 10000 sixteen-edge waves
#define NF 128
#define NB 20
#define CUT 5.0f
#define TPS 136        // u16 tile row stride
#define MAXSEG 21000   // >= NN + NW - 1 bound on total segments

typedef __attribute__((ext_vector_type(8))) short short8;
typedef __attribute__((ext_vector_type(4))) float floatx4;
typedef unsigned short u16;
typedef unsigned int u32;

__device__ __forceinline__ u16 f2b(float x){
  union { __hip_bfloat16 b; u16 u; } cv;
  cv.b = __float2bfloat16(x);
  return cv.u;
}
__device__ __forceinline__ float b2f_raw(u16 x){ return __uint_as_float((u32)x << 16); }
__device__ __forceinline__ float lo_bf(u32 w){ return __uint_as_float(w << 16); }
__device__ __forceinline__ float hi_bf(u32 w){ return __uint_as_float(w & 0xFFFF0000u); }
__device__ __forceinline__ u32 packbf(float lo, float hi){
  return ((u32)f2b(hi) << 16) | (u32)f2b(lo);
}
__device__ __forceinline__ float fast_silu(float v){
  return v * __builtin_amdgcn_rcpf(1.f + __expf(-v));
}
__device__ __forceinline__ float rdf(const void* p, size_t i, int isb){
  return isb ? __bfloat162float(((const __hip_bfloat16*)p)[i]) : ((const float*)p)[i];
}

// ---------------- dtype detector: 1=bf16, 0=fp32 ----------------
__global__ __launch_bounds__(256) void k_detect(const void* __restrict__ w, int nelem,
                                                int* __restrict__ flag){
  __shared__ int cnt;
  if (threadIdx.x == 0) cnt = 0;
  __syncthreads();
  const u16* hw = (const u16*)w;
  int local = 0;
  for (int k = threadIdx.x; k < nelem; k += 256){
    u16 h = hw[k];
    int e = (h >> 7) & 0xFF;
    if ((h & 0x7FFF) == 0 || (e >= 103 && e <= 130)) local++;
  }
  atomicAdd(&cnt, local);
  __syncthreads();
  if (threadIdx.x == 0) *flag = (cnt >= (nelem * 9) / 10) ? 1 : 0;
}

// ---------------- fused convert-to-fp32 (4 tensors) ----------------
struct CvtArgs { const void* src[4]; float* dst[4]; int n[4]; };
__global__ __launch_bounds__(256) void k_cvt4(CvtArgs a, const int* __restrict__ flag){
  int y = blockIdx.y;
  int isb = *flag;
  const void* s = a.src[y]; float* d = a.dst[y]; int n = a.n[y];
  for (int i = blockIdx.x*256 + threadIdx.x; i < n; i += gridDim.x*256)
    d[i] = rdf(s, i, isb);
}

// ---------------- fused weight swizzle (7 128x128 matrices) ----------------
struct SwzArgs { const void* src[7]; u16* dst[7]; };
__global__ __launch_bounds__(256) void k_swz7(SwzArgs a, const int* __restrict__ flag){
  int y = blockIdx.y;
  int isb = *flag;
  const void* s = a.src[y]; u16* d = a.dst[y];
  int idx = blockIdx.x*256 + threadIdx.x;        // 192*256 = 3*16384
  int l = idx >> 14, rem = idx & 16383;
  int j = rem & 7, lane = (rem >> 3) & 63, tn = (rem >> 9) & 7, tk = rem >> 12;
  int k = tk*32 + ((lane >> 4) & 3)*8 + j, n = tn*16 + (lane & 15);
  d[idx] = f2b(rdf(s, (size_t)l*16384 + k*NF + n, isb));
}
__global__ __launch_bounds__(256) void k_swzme(const void* __restrict__ W, u16* __restrict__ out,
                                               const int* __restrict__ flag){
  int idx = blockIdx.x*256 + threadIdx.x;     // 3*4096
  if (idx >= 3*4096) return;
  int isb = *flag;
  int l = idx >> 12, rem = idx & 4095;
  int j = rem & 7, lane = (rem >> 3) & 63, tn = rem >> 9;
  int k = ((lane >> 4) & 3)*8 + j, n = tn*16 + (lane & 15);
  out[idx] = (k < NB) ? f2b(rdf(W, (size_t)l*NB*NF + k*NF + n, isb)) : (u16)0;
}

// ---------------- counting sort of edges by destination i ----------------
__global__ __launch_bounds__(256) void k_hist(const int* __restrict__ ei, int* __restrict__ count){
  int e = blockIdx.x*256 + threadIdx.x;
  if (e < NE) atomicAdd(&count[ei[e]], 1);
}
__global__ __launch_bounds__(256) void k_scan(const int* __restrict__ count,
                                              int* __restrict__ rowptr, int* __restrict__ cursor){
  __shared__ int part[256];
  const int CH = (NN + 255) / 256;
  int t = threadIdx.x;
  int base = t * CH;
  int s = 0;
  for (int k = 0; k < CH; k++){ int i = base + k; if (i < NN) s += count[i]; }
  part[t] = s;
  __syncthreads();
  for (int off = 1; off < 256; off <<= 1){
    int v = (t >= off) ? part[t - off] : 0;
    __syncthreads();
    part[t] += v;
    __syncthreads();
  }
  int run = (t == 0) ? 0 : part[t - 1];
  for (int k = 0; k < CH; k++){
    int i = base + k;
    if (i < NN){ rowptr[i] = run; cursor[i] = run; run += count[i]; }
  }
  if (t == 255) rowptr[NN] = run;
}
// generic single-block exclusive scan, dst[n] = total
__global__ __launch_bounds__(256) void k_scan_g(const int* __restrict__ src,
                                                int* __restrict__ dst, int n){
  __shared__ int part[256];
  int CH = (n + 255) / 256;
  int t = threadIdx.x, base = t * CH, s = 0;
  for (int k = 0; k < CH; k++){ int i = base + k; if (i < n) s += src[i]; }
  part[t] = s;
  __syncthreads();
  for (int off = 1; off < 256; off <<= 1){
    int v = (t >= off) ? part[t - off] : 0;
    __syncthreads();
    part[t] += v;
    __syncthreads();
  }
  int run = (t == 0) ? 0 : part[t - 1];
  for (int k = 0; k < CH; k++){
    int i = base + k;
    if (i < n){ dst[i] = run; run += src[i]; }
  }
  if (t == 255) dst[n] = run;
}
__global__ __launch_bounds__(256) void k_scatter(const int* __restrict__ ei,
                                                 int* __restrict__ cursor, int* __restrict__ perm){
  int e = blockIdx.x*256 + threadIdx.x;
  if (e >= NE) return;
  int pos = atomicAdd(&cursor[ei[e]], 1);
  perm[pos] = e;
}
// per-wave distinct-destination count
__global__ __launch_bounds__(256) void k_wavecnt(const int* __restrict__ iis, int* __restrict__ wcnt){
  int w = blockIdx.x*256 + threadIdx.x;
  if (w >= NW) return;
  int prev = iis[w*16], c = 1;
  for (int m = 1; m < 16; m++){ int v = iis[w*16 + m]; c += (v != prev); prev = v; }
  wcnt[w] = c;
}
// per-node segment count (= #waves its sorted edge range touches)
__global__ __launch_bounds__(256) void k_nodesegcnt(const int* __restrict__ rowptr, int* __restrict__ ncnt){
  int n = blockIdx.x*256 + threadIdx.x;
  if (n >= NN) return;
  int a = rowptr[n], b = rowptr[n+1];
  ncnt[n] = (b > a) ? (((b-1) >> 4) - (a >> 4) + 1) : 0;
}

// ---------------- init atom ----------------
__global__ __launch_bounds__(256) void k_init_atom(const int* __restrict__ z,
                                                   const float* __restrict__ emb,
                                                   float* __restrict__ atom){
  int idx = blockIdx.x * 256 + threadIdx.x;
  if (idx >= NN * NF) return;
  int n = idx >> 7, f = idx & (NF - 1);
  atom[idx] = emb[z[n] * NF + f];
}

// ---------------- edge embedding into SORTED slots ----------------
__global__ __launch_bounds__(256) void k_edge_embed(const int* __restrict__ ei,
                                                    const int* __restrict__ perm,
                                                    const float* __restrict__ pos,
                                                    int* __restrict__ iis, int* __restrict__ jjs,
                                                    float* __restrict__ ds, float* __restrict__ dirs){
  int s = blockIdx.x * 256 + threadIdx.x;
  if (s >= NE) return;
  int e = perm[s];
  int i = ei[e], j = ei[NE + e];
  float dx = pos[j*3+0] - pos[i*3+0];
  float dy = pos[j*3+1] - pos[i*3+1];
  float dz = pos[j*3+2] - pos[i*3+2];
  float d = sqrtf(dx*dx + dy*dy + dz*dz + 1e-12f);
  float inv = 1.0f / d;
  iis[s] = i; jjs[s] = j;
  ds[s] = d;
  dirs[s*3+0] = dx*inv; dirs[s*3+1] = dy*inv; dirs[s*3+2] = dz*inv;
}

// ---------------- fused node MLP (MFMA, 4 waves/block, barrier-free) ----------------
__global__ __launch_bounds__(256, 4) void k_node_mlp2(
    const float* __restrict__ atom,
    const u16* __restrict__ w1sw, const float* __restrict__ b1,
    const u16* __restrict__ w2sw, const float* __restrict__ b2,
    u32* __restrict__ hb)
{
  __shared__ __align__(16) u16 tileT[4][16][TPS];
  const int wv = threadIdx.x >> 6, lane = threadIdx.x & 63;
  const int q = lane >> 4, ln = lane & 15;
  const int n0 = (blockIdx.x*4 + wv) * 16;
  if (n0 >= NN) return;

  floatx4 c1[8];
  #pragma unroll
  for (int tn = 0; tn < 8; tn++) c1[tn] = (floatx4){0,0,0,0};
  #pragma unroll
  for (int tk = 0; tk < 4; tk++){
    const float4 u0 = *(const float4*)&atom[(size_t)(n0+ln)*NF + tk*32 + q*8];
    const float4 u1 = *(const float4*)&atom[(size_t)(n0+ln)*NF + tk*32 + q*8 + 4];
    short8 a;
    a[0]=(short)f2b(u0.x); a[1]=(short)f2b(u0.y); a[2]=(short)f2b(u0.z); a[3]=(short)f2b(u0.w);
    a[4]=(short)f2b(u1.x); a[5]=(short)f2b(u1.y); a[6]=(short)f2b(u1.z); a[7]=(short)f2b(u1.w);
    #pragma unroll
    for (int tn = 0; tn < 8; tn++){
      short8 b = *(const short8*)(w1sw + (size_t)((tk*8 + tn)*64 + lane)*8);
      c1[tn] = __builtin_amdgcn_mfma_f32_16x16x32_bf16(a, b, c1[tn], 0, 0, 0);
    }
  }
  #pragma unroll
  for (int tn = 0; tn < 8; tn++){
    int n = tn*16 + ln;
    float bias = b1[n];
    #pragma unroll
    for (int r = 0; r < 4; r++)
      tileT[wv][q*4 + r][n] = f2b(fast_silu(c1[tn][r] + bias));
  }

  floatx4 c2[8];
  #pragma unroll
  for (int tn = 0; tn < 8; tn++) c2[tn] = (floatx4){0,0,0,0};
  #pragma unroll
  for (int tk = 0; tk < 4; tk++){
    short8 a = *(const short8*)&tileT[wv][ln][tk*32 + q*8];
    #pragma unroll
    for (int tn = 0; tn < 8; tn++){
      short8 b = *(const short8*)(w2sw + (size_t)((tk*8 + tn)*64 + lane)*8);
      c2[tn] = __builtin_amdgcn_mfma_f32_16x16x32_bf16(a, b, c2[tn], 0, 0, 0);
    }
  }
  float b2n[8];
  #pragma unroll
  for (int tn = 0; tn < 8; tn++) b2n[tn] = b2[tn*16 + ln];
  #pragma unroll
  for (int tn = 0; tn < 4; tn++){
    #pragma unroll
    for (int r = 0; r < 4; r++){
      float vl = c2[tn][r]   + b2n[tn];
      float vh = c2[tn+4][r] + b2n[tn+4];
      hb[(size_t)(n0 + q*4 + r)*64 + tn*16 + ln] = packbf(vl, vh);
    }
  }
}

// ---------------- MFMA edge kernel: atomic-free, per-wave segment partials ----------------
// Accumulator lifetimes sequenced (t1->tileT, t2->tileM) so peak = g1+g2 = 64 regs,
// under the (256,4) 128-reg cap. (r7: 64-cap spilled 1.2GB; r8: 96-live spilled ~38 regs.)
__global__ __launch_bounds__(256, 4) void k_edge_mfma(
    const int* __restrict__ iis, const int* __restrict__ jjs,
    const float* __restrict__ ds, const float* __restrict__ dirs,
    const u32* __restrict__ hb, const int* __restrict__ wavebase,
    const u16* __restrict__ mesw,
    const u16* __restrict__ w11sw, const u16* __restrict__ w12sw,
    const u16* __restrict__ w21sw, const u16* __restrict__ w22sw,
    const u32* __restrict__ forceb,
    float* __restrict__ msgpart, float* __restrict__ fpart)
{
  __shared__ __align__(16) u16 tileM[4][16][TPS];
  __shared__ __align__(16) u16 tileT[4][16][TPS];
  __shared__ int iiS[4][16];

  const int wv   = threadIdx.x >> 6;
  const int lane = threadIdx.x & 63;
  const int q = lane >> 4, ln = lane & 15;
  const int w  = blockIdx.x*4 + wv;      // grid = NW/4 exactly
  const int e0 = w * 16;

  if (lane < 16) iiS[wv][lane] = iis[e0 + lane];
  const int base = wavebase[w];

  int iiR[4], jjR[4];
  float dirR[4][3];
  #pragma unroll
  for (int r = 0; r < 4; r++){
    int s = e0 + q*4 + r;
    iiR[r] = iis[s]; jjR[r] = jjs[s];
    dirR[r][0] = dirs[s*3+0]; dirR[r][1] = dirs[s*3+1]; dirR[r][2] = dirs[s*3+2];
  }

  // paired h gathers
  u32 hiw[4][4], hjw[4][4];
  #pragma unroll
  for (int r = 0; r < 4; r++)
    #pragma unroll
    for (int t4 = 0; t4 < 4; t4++){
      hiw[r][t4] = hb[(size_t)iiR[r]*64 + t4*16 + ln];
      hjw[r][t4] = hb[(size_t)jjR[r]*64 + t4*16 + ln];
    }

  // rbf A-fragment (K padded 20->32)
  float dA  = ds[e0 + ln];
  float fcA = (dA < CUT) ? 0.5f*(cosf((float)M_PI*dA*(1.0f/CUT)) + 1.0f) : 0.0f;
  short8 a_rbf;
  #pragma unroll
  for (int j = 0; j < 8; j++){
    int k = q*8 + j;
    float v = 0.f;
    if (k < NB){
      float t = (dA - CUT*(float)k/(float)(NB-1)) * ((float)NB/CUT);
      v = __expf(-t*t) * fcA;
    }
    a_rbf[j] = (short)f2b(v);
  }

  // me = rbf @ meW; msg = me*h_i*h_j -> tileM (bf16)
  #pragma unroll
  for (int tn = 0; tn < 8; tn++){
    short8 b = *(const short8*)(mesw + (size_t)(tn*64 + lane)*8);
    floatx4 c = {0.f,0.f,0.f,0.f};
    c = __builtin_amdgcn_mfma_f32_16x16x32_bf16(a_rbf, b, c, 0, 0, 0);
    int n = tn*16 + ln;
    int t4 = tn & 3;
    #pragma unroll
    for (int r = 0; r < 4; r++){
      float hi_ = (tn < 4) ? lo_bf(hiw[r][t4]) : hi_bf(hiw[r][t4]);
      float hj_ = (tn < 4) ? lo_bf(hjw[r][t4]) : hi_bf(hjw[r][t4]);
      tileM[wv][q*4 + r][n] = f2b(c[r] * hi_ * hj_);
    }
  }

  // atom segment partials -> msgpart (plain stores, no atomics)
  {
    int l = 0, seg = 0;
    for (int m = 1; m <= 16; m++){
      if (m == 16 || iiS[wv][m] != iiS[wv][seg]){
        for (int c = lane; c < NF; c += 64){
          float s = 0.f;
          for (int r = seg; r < m; r++) s += b2f_raw(tileM[wv][r][c]);
          msgpart[(size_t)(base + l)*NF + c] = s;
        }
        l++; seg = m;
      }
    }
  }

  // t1 = silu(msg @ w11) -> tileT   (accumulator freed after)
  {
    floatx4 c[8];
    #pragma unroll
    for (int tn = 0; tn < 8; tn++) c[tn] = (floatx4){0,0,0,0};
    #pragma unroll
    for (int tk = 0; tk < 4; tk++){
      short8 a = *(const short8*)&tileM[wv][ln][tk*32 + q*8];
      #pragma unroll
      for (int tn = 0; tn < 8; tn++){
        short8 b = *(const short8*)(w11sw + (size_t)((tk*8 + tn)*64 + lane)*8);
        c[tn] = __builtin_amdgcn_mfma_f32_16x16x32_bf16(a, b, c[tn], 0, 0, 0);
      }
    }
    #pragma unroll
    for (int tn = 0; tn < 8; tn++){
      int n = tn*16 + ln;
      #pragma unroll
      for (int r = 0; r < 4; r++)
        tileT[wv][q*4 + r][n] = f2b(fast_silu(c[tn][r]));
    }
  }
  // t2 = silu(msg @ w21) -> tileM (msg dead after the reads in this pass)
  {
    floatx4 c[8];
    #pragma unroll
    for (int tn = 0; tn < 8; tn++) c[tn] = (floatx4){0,0,0,0};
    #pragma unroll
    for (int tk = 0; tk < 4; tk++){
      short8 a = *(const short8*)&tileM[wv][ln][tk*32 + q*8];
      #pragma unroll
      for (int tn = 0; tn < 8; tn++){
        short8 b = *(const short8*)(w21sw + (size_t)((tk*8 + tn)*64 + lane)*8);
        c[tn] = __builtin_amdgcn_mfma_f32_16x16x32_bf16(a, b, c[tn], 0, 0, 0);
      }
    }
    #pragma unroll
    for (int tn = 0; tn < 8; tn++){
      int n = tn*16 + ln;
      #pragma unroll
      for (int r = 0; r < 4; r++)
        tileM[wv][q*4 + r][n] = f2b(fast_silu(c[tn][r]));
    }
  }

  // g1 = t1 @ w12 (from tileT)
  floatx4 g1[8];
  #pragma unroll
  for (int tn = 0; tn < 8; tn++) g1[tn] = (floatx4){0,0,0,0};
  #pragma unroll
  for (int tk = 0; tk < 4; tk++){
    short8 a = *(const short8*)&tileT[wv][ln][tk*32 + q*8];
    #pragma unroll
    for (int tn = 0; tn < 8; tn++){
      short8 b = *(const short8*)(w12sw + (size_t)((tk*8 + tn)*64 + lane)*8);
      g1[tn] = __builtin_amdgcn_mfma_f32_16x16x32_bf16(a, b, g1[tn], 0, 0, 0);
    }
  }
  // g2 = t2 @ w22 (from tileM)
  floatx4 g2[8];
  #pragma unroll
  for (int tn = 0; tn < 8; tn++) g2[tn] = (floatx4){0,0,0,0};
  #pragma unroll
  for (int tk = 0; tk < 4; tk++){
    short8 a = *(const short8*)&tileM[wv][ln][tk*32 + q*8];
    #pragma unroll
    for (int tn = 0; tn < 8; tn++){
      short8 b = *(const short8*)(w22sw + (size_t)((tk*8 + tn)*64 + lane)*8);
      g2[tn] = __builtin_amdgcn_mfma_f32_16x16x32_bf16(a, b, g2[tn], 0, 0, 0);
    }
  }

  // three d-passes: stage into tileT, segment-reduce -> fpart
  for (int d = 0; d < 3; d++){
    u32 fjw[4][4];
    #pragma unroll
    for (int r = 0; r < 4; r++)
      #pragma unroll
      for (int t4 = 0; t4 < 4; t4++)
        fjw[r][t4] = forceb[((size_t)jjR[r]*3 + d)*64 + t4*16 + ln];
    #pragma unroll
    for (int tn = 0; tn < 8; tn++){
      int n = tn*16 + ln;
      int t4 = tn & 3;
      #pragma unroll
      for (int r = 0; r < 4; r++){
        float fj = (tn < 4) ? lo_bf(fjw[r][t4]) : hi_bf(fjw[r][t4]);
        tileT[wv][q*4 + r][n] = f2b(g1[tn][r]*dirR[r][d] + g2[tn][r]*fj);
      }
    }
    int l = 0, seg = 0;
    for (int m = 1; m <= 16; m++){
      if (m == 16 || iiS[wv][m] != iiS[wv][seg]){
        for (int c = lane; c < NF; c += 64){
          float s = 0.f;
          for (int r = seg; r < m; r++) s += b2f_raw(tileT[wv][r][c]);
          fpart[((size_t)(base + l)*3 + d)*NF + c] = s;
        }
        l++; seg = m;
      }
    }
  }
}

// ---------------- node update: aggregate partials + force update + forceb + eu term ----------------
__global__ __launch_bounds__(256, 4) void k_node_update(
    float* __restrict__ force,
    const float* __restrict__ msgpart, const float* __restrict__ fpart,
    const int* __restrict__ segptr,
    const u16* __restrict__ eusw, float* __restrict__ atom,
    u32* __restrict__ forceb)
{
  __shared__ __align__(16) u16 tile[4][16][TPS];
  __shared__ int spS[4][17];
  const int wv = threadIdx.x >> 6, lane = threadIdx.x & 63;
  const int q = lane >> 4, ln = lane & 15;
  const int n0 = (blockIdx.x*4 + wv) * 16;
  if (n0 >= NN) return;
  if (lane < 17) spS[wv][lane] = segptr[n0 + lane];

  // atom += per-node msg aggregation (exclusive rows, plain r-m-w)
  #pragma unroll 2
  for (int m = 0; m < 16; m++){
    int a = spS[wv][m], b = spS[wv][m+1];
    float s0 = 0.f, s1 = 0.f;
    for (int t = a; t < b; t++){
      s0 += msgpart[(size_t)t*NF + lane];
      s1 += msgpart[(size_t)t*NF + lane + 64];
    }
    size_t idx = (size_t)(n0+m)*NF + lane;
    atom[idx]    += s0;
    atom[idx+64] += s1;
  }

  floatx4 sacc[8];
  #pragma unroll
  for (int tn = 0; tn < 8; tn++) sacc[tn] = (floatx4){0,0,0,0};

  for (int d = 0; d < 3; d++){
    #pragma unroll 2
    for (int m = 0; m < 16; m++){
      int a = spS[wv][m], b = spS[wv][m+1];
      size_t idx = ((size_t)(n0+m)*3 + d)*NF + lane;
      float v0 = force[idx], v1 = force[idx+64];
      for (int t = a; t < b; t++){
        v0 += fpart[((size_t)t*3 + d)*NF + lane];
        v1 += fpart[((size_t)t*3 + d)*NF + lane + 64];
      }
      force[idx] = v0; force[idx+64] = v1;
      forceb[((size_t)(n0+m)*3 + d)*64 + lane] = packbf(v0, v1);
      tile[wv][m][lane]    = f2b(v0);
      tile[wv][m][lane+64] = f2b(v1);
    }
    // t_d = force_d @ euW
    floatx4 c[8];
    #pragma unroll
    for (int tn = 0; tn < 8; tn++) c[tn] = (floatx4){0,0,0,0};
    #pragma unroll
    for (int tk = 0; tk < 4; tk++){
      short8 a = *(const short8*)&tile[wv][ln][tk*32 + q*8];
      #pragma unroll
      for (int tn = 0; tn < 8; tn++){
        short8 b = *(const short8*)(eusw + (size_t)((tk*8 + tn)*64 + lane)*8);
        c[tn] = __builtin_amdgcn_mfma_f32_16x16x32_bf16(a, b, c[tn], 0, 0, 0);
      }
    }
    #pragma unroll
    for (int tn = 0; tn < 8; tn++){
      int n = tn*16 + ln;
      #pragma unroll
      for (int r = 0; r < 4; r++)
        sacc[tn][r] += b2f_raw(tile[wv][q*4 + r][n]) * c[tn][r];
    }
  }
  // atom += eu term (C-layout, exclusive rows; same-wave ordering vs phase-1 enforced
  // by compiler's conservative aliasing on `atom`)
  #pragma unroll
  for (int tn = 0; tn < 8; tn++){
    int n = tn*16 + ln;
    #pragma unroll
    for (int r = 0; r < 4; r++){
      size_t idx = (size_t)(n0 + q*4 + r)*NF + n;
      atom[idx] += sacc[tn][r];
    }
  }
}

// ---------------- write out ----------------
__global__ __launch_bounds__(256) void k_writeout(const float* __restrict__ atom,
                                                  const float* __restrict__ force,
                                                  void* __restrict__ out,
                                                  const int* __restrict__ flag){
  int idx = blockIdx.x * 256 + threadIdx.x;
  const int na = NN * NF;
  const int tot = na + NN * 3 * NF;
  if (idx >= tot) return;
  float v = (idx < na) ? atom[idx] : force[idx - na];
  if (*flag) ((__hip_bfloat16*)out)[idx] = __float2bfloat16(v);
  else       ((float*)out)[idx] = v;
}

extern "C" void kernel_launch(void* const* d_in, const int* in_sizes, int n_in,
                              void* d_out, int out_size, void* d_ws, size_t ws_size,
                              hipStream_t stream){
  const int* z    = (const int*)d_in[0];
  const void* pos = d_in[1];
  // d_in[2] cell, d_in[3] batch: numerically dead (sym == I)
  const int* ei   = (const int*)d_in[4];
  const void* emb   = d_in[5];
  const void* mnpW1 = d_in[6];
  const void* mnpb1 = d_in[7];
  const void* mnpW2 = d_in[8];
  const void* mnpb2 = d_in[9];
  const void* meW   = d_in[10];
  const void* em1W1 = d_in[11];
  const void* em1W2 = d_in[12];
  const void* em2W1 = d_in[13];
  const void* em2W2 = d_in[14];
  const void* euW   = d_in[15];

  float* base  = (float*)d_ws;
  int*   flag  = (int*)d_ws;                  // 4 floats reserved
  float* atom   = base + 4;                   // NN*NF
  float* force  = atom   + NN*NF;             // NN*3*NF
  u32*   forceb = (u32*)(force + (size_t)NN*3*NF);   // NN*3*64
  int*   count  = (int*)(forceb + (size_t)NN*3*64);  // NN
  // memset zeroes force + forceb + count (contiguous)
  float* ds    = (float*)(count + NN);
  float* dirs  = ds + NE;
  float* posf  = dirs + 3*NE;
  float* embf  = posf + NN*3;
  float* b1f   = embf + 119*NF;               // 3*NF
  float* b2f_  = b1f + 3*NF;                  // 3*NF
  u32*   hb    = (u32*)(b2f_ + 3*NF);         // NN*64
  u16*   mesw  = (u16*)(hb + (size_t)NN*64);  // 3*4096
  u16*   w11sw = mesw  + 3*4096;
  u16*   w12sw = w11sw + 3*16384;
  u16*   w21sw = w12sw + 3*16384;
  u16*   w22sw = w21sw + 3*16384;
  u16*   w1sw  = w22sw + 3*16384;
  u16*   w2sw  = w1sw  + 3*16384;
  u16*   eusw  = w2sw  + 3*16384;
  int* rowptr  = (int*)(eusw + 3*16384);      // NN+1
  int* cursor  = rowptr + NN + 1;
  int* perm    = cursor + NN;                 // NE
  int* iis     = perm + NE;
  int* jjs     = iis + NE;
  int* wcnt    = jjs + NE;                    // NW
  int* wavebase= wcnt + NW;                   // NW+1
  int* ncnt    = wavebase + NW + 1;           // NN
  int* segptr  = ncnt + NN;                   // NN+1
  float* msgpart = (float*)(segptr + NN + 1); // MAXSEG*NF
  float* fpart   = msgpart + (size_t)MAXSEG*NF;  // MAXSEG*3*NF

  k_detect<<<1, 256, 0, stream>>>(meW, 3*NB*NF, flag);

  // zero force + forceb + count in one shot
  hipMemsetAsync(force, 0, ((size_t)NN*3*NF + (size_t)NN*3*64 + NN)*4, stream);

  CvtArgs ca;
  ca.src[0]=pos;   ca.dst[0]=posf; ca.n[0]=NN*3;
  ca.src[1]=emb;   ca.dst[1]=embf; ca.n[1]=119*NF;
  ca.src[2]=mnpb1; ca.dst[2]=b1f;  ca.n[2]=3*NF;
  ca.src[3]=mnpb2; ca.dst[3]=b2f_; ca.n[3]=3*NF;
  k_cvt4<<<dim3(60,4), 256, 0, stream>>>(ca, flag);

  SwzArgs sa;
  sa.src[0]=em1W1; sa.dst[0]=w11sw;
  sa.src[1]=em1W2; sa.dst[1]=w12sw;
  sa.src[2]=em2W1; sa.dst[2]=w21sw;
  sa.src[3]=em2W2; sa.dst[3]=w22sw;
  sa.src[4]=mnpW1; sa.dst[4]=w1sw;
  sa.src[5]=mnpW2; sa.dst[5]=w2sw;
  sa.src[6]=euW;   sa.dst[6]=eusw;
  k_swz7 <<<dim3(192,7), 256, 0, stream>>>(sa, flag);
  k_swzme<<<(3*4096+255)/256, 256, 0, stream>>>(meW, mesw, flag);

  k_hist      <<<(NE+255)/256, 256, 0, stream>>>(ei, count);
  k_scan      <<<1, 256, 0, stream>>>(count, rowptr, cursor);
  k_scatter   <<<(NE+255)/256, 256, 0, stream>>>(ei, cursor, perm);
  k_edge_embed<<<(NE+255)/256, 256, 0, stream>>>(ei, perm, posf, iis, jjs, ds, dirs);
  k_wavecnt   <<<(NW+255)/256, 256, 0, stream>>>(iis, wcnt);
  k_scan_g    <<<1, 256, 0, stream>>>(wcnt, wavebase, NW);
  k_nodesegcnt<<<(NN+255)/256, 256, 0, stream>>>(rowptr, ncnt);
  k_scan_g    <<<1, 256, 0, stream>>>(ncnt, segptr, NN);
  k_init_atom <<<(NN*NF+255)/256, 256, 0, stream>>>(z, embf, atom);

  for (int l = 0; l < 3; l++){
    k_node_mlp2<<<(NN/16 + 3)/4, 256, 0, stream>>>(atom,
        w1sw + (size_t)l*16384, b1f + (size_t)l*NF,
        w2sw + (size_t)l*16384, b2f_ + (size_t)l*NF, hb);
    k_edge_mfma<<<NW/4, 256, 0, stream>>>(iis, jjs, ds, dirs, hb, wavebase,
        mesw  + (size_t)l*4096,
        w11sw + (size_t)l*16384, w12sw + (size_t)l*16384,
        w21sw + (size_t)l*16384, w22sw + (size_t)l*16384,
        forceb, msgpart, fpart);
    k_node_update<<<(NN/16 + 3)/4, 256, 0, stream>>>(force, msgpart, fpart,
        segptr, eusw + (size_t)l*16384, atom, forceb);
  }

  k_writeout<<<(NN*NF + NN*3*NF + 255)/256, 256, 0, stream>>>(atom, force, d_out, flag);
}

// Round 10
// 801.478 us; speedup vs baseline: 1.1546x; 1.1546x over previous
//
#include <hip/hip_runtime.h>
#include <hip/hip_bf16.h>
#include <math.h>

#define NN 10000
#define NE 160000
#define NW (NE/16)     // 10000 sixteen-edge waves
#define NF 128
#define NB 20
#define CUT 5.0f
#define TPS 136        // u16 tile row stride
#define MAXSEG 21000   // >= NN + NW - 1 bound on total segments

typedef __attribute__((ext_vector_type(8))) short short8;
typedef __attribute__((ext_vector_type(4))) float floatx4;
typedef unsigned short u16;
typedef unsigned int u32;

__device__ __forceinline__ u16 f2b(float x){
  union { __hip_bfloat16 b; u16 u; } cv;
  cv.b = __float2bfloat16(x);
  return cv.u;
}
__device__ __forceinline__ float b2f_raw(u16 x){ return __uint_as_float((u32)x << 16); }
__device__ __forceinline__ float lo_bf(u32 w){ return __uint_as_float(w << 16); }
__device__ __forceinline__ float hi_bf(u32 w){ return __uint_as_float(w & 0xFFFF0000u); }
__device__ __forceinline__ u32 packbf(float lo, float hi){
  return ((u32)f2b(hi) << 16) | (u32)f2b(lo);
}
__device__ __forceinline__ float fast_silu(float v){
  return v * __builtin_amdgcn_rcpf(1.f + __expf(-v));
}
__device__ __forceinline__ float rdf(const void* p, size_t i, int isb){
  return isb ? __bfloat162float(((const __hip_bfloat16*)p)[i]) : ((const float*)p)[i];
}

// ---------------- dtype detector: 1=bf16, 0=fp32 ----------------
__global__ __launch_bounds__(256) void k_detect(const void* __restrict__ w, int nelem,
                                                int* __restrict__ flag){
  __shared__ int cnt;
  if (threadIdx.x == 0) cnt = 0;
  __syncthreads();
  const u16* hw = (const u16*)w;
  int local = 0;
  for (int k = threadIdx.x; k < nelem; k += 256){
    u16 h = hw[k];
    int e = (h >> 7) & 0xFF;
    if ((h & 0x7FFF) == 0 || (e >= 103 && e <= 130)) local++;
  }
  atomicAdd(&cnt, local);
  __syncthreads();
  if (threadIdx.x == 0) *flag = (cnt >= (nelem * 9) / 10) ? 1 : 0;
}

// ---------------- fused convert-to-fp32 (4 tensors) ----------------
struct CvtArgs { const void* src[4]; float* dst[4]; int n[4]; };
__global__ __launch_bounds__(256) void k_cvt4(CvtArgs a, const int* __restrict__ flag){
  int y = blockIdx.y;
  int isb = *flag;
  const void* s = a.src[y]; float* d = a.dst[y]; int n = a.n[y];
  for (int i = blockIdx.x*256 + threadIdx.x; i < n; i += gridDim.x*256)
    d[i] = rdf(s, i, isb);
}

// ---------------- fused weight swizzle (7 128x128 matrices) ----------------
struct SwzArgs { const void* src[7]; u16* dst[7]; };
__global__ __launch_bounds__(256) void k_swz7(SwzArgs a, const int* __restrict__ flag){
  int y = blockIdx.y;
  int isb = *flag;
  const void* s = a.src[y]; u16* d = a.dst[y];
  int idx = blockIdx.x*256 + threadIdx.x;        // 192*256 = 3*16384
  int l = idx >> 14, rem = idx & 16383;
  int j = rem & 7, lane = (rem >> 3) & 63, tn = (rem >> 9) & 7, tk = rem >> 12;
  int k = tk*32 + ((lane >> 4) & 3)*8 + j, n = tn*16 + (lane & 15);
  d[idx] = f2b(rdf(s, (size_t)l*16384 + k*NF + n, isb));
}
__global__ __launch_bounds__(256) void k_swzme(const void* __restrict__ W, u16* __restrict__ out,
                                               const int* __restrict__ flag){
  int idx = blockIdx.x*256 + threadIdx.x;     // 3*4096
  if (idx >= 3*4096) return;
  int isb = *flag;
  int l = idx >> 12, rem = idx & 4095;
  int j = rem & 7, lane = (rem >> 3) & 63, tn = rem >> 9;
  int k = ((lane >> 4) & 3)*8 + j, n = tn*16 + (lane & 15);
  out[idx] = (k < NB) ? f2b(rdf(W, (size_t)l*NB*NF + k*NF + n, isb)) : (u16)0;
}

// ---------------- counting sort of edges by destination i ----------------
__global__ __launch_bounds__(256) void k_hist(const int* __restrict__ ei, int* __restrict__ count){
  int e = blockIdx.x*256 + threadIdx.x;
  if (e < NE) atomicAdd(&count[ei[e]], 1);
}
__global__ __launch_bounds__(256) void k_scan(const int* __restrict__ count,
                                              int* __restrict__ rowptr, int* __restrict__ cursor){
  __shared__ int part[256];
  const int CH = (NN + 255) / 256;
  int t = threadIdx.x;
  int base = t * CH;
  int s = 0;
  for (int k = 0; k < CH; k++){ int i = base + k; if (i < NN) s += count[i]; }
  part[t] = s;
  __syncthreads();
  for (int off = 1; off < 256; off <<= 1){
    int v = (t >= off) ? part[t - off] : 0;
    __syncthreads();
    part[t] += v;
    __syncthreads();
  }
  int run = (t == 0) ? 0 : part[t - 1];
  for (int k = 0; k < CH; k++){
    int i = base + k;
    if (i < NN){ rowptr[i] = run; cursor[i] = run; run += count[i]; }
  }
  if (t == 255) rowptr[NN] = run;
}
// generic single-block exclusive scan, dst[n] = total
__global__ __launch_bounds__(256) void k_scan_g(const int* __restrict__ src,
                                                int* __restrict__ dst, int n){
  __shared__ int part[256];
  int CH = (n + 255) / 256;
  int t = threadIdx.x, base = t * CH, s = 0;
  for (int k = 0; k < CH; k++){ int i = base + k; if (i < n) s += src[i]; }
  part[t] = s;
  __syncthreads();
  for (int off = 1; off < 256; off <<= 1){
    int v = (t >= off) ? part[t - off] : 0;
    __syncthreads();
    part[t] += v;
    __syncthreads();
  }
  int run = (t == 0) ? 0 : part[t - 1];
  for (int k = 0; k < CH; k++){
    int i = base + k;
    if (i < n){ dst[i] = run; run += src[i]; }
  }
  if (t == 255) dst[n] = run;
}
__global__ __launch_bounds__(256) void k_scatter(const int* __restrict__ ei,
                                                 int* __restrict__ cursor, int* __restrict__ perm){
  int e = blockIdx.x*256 + threadIdx.x;
  if (e >= NE) return;
  int pos = atomicAdd(&cursor[ei[e]], 1);
  perm[pos] = e;
}
// per-wave distinct-destination count
__global__ __launch_bounds__(256) void k_wavecnt(const int* __restrict__ iis, int* __restrict__ wcnt){
  int w = blockIdx.x*256 + threadIdx.x;
  if (w >= NW) return;
  int prev = iis[w*16], c = 1;
  for (int m = 1; m < 16; m++){ int v = iis[w*16 + m]; c += (v != prev); prev = v; }
  wcnt[w] = c;
}
// per-node segment count (= #waves its sorted edge range touches)
__global__ __launch_bounds__(256) void k_nodesegcnt(const int* __restrict__ rowptr, int* __restrict__ ncnt){
  int n = blockIdx.x*256 + threadIdx.x;
  if (n >= NN) return;
  int a = rowptr[n], b = rowptr[n+1];
  ncnt[n] = (b > a) ? (((b-1) >> 4) - (a >> 4) + 1) : 0;
}

// ---------------- init atom ----------------
__global__ __launch_bounds__(256) void k_init_atom(const int* __restrict__ z,
                                                   const float* __restrict__ emb,
                                                   float* __restrict__ atom){
  int idx = blockIdx.x * 256 + threadIdx.x;
  if (idx >= NN * NF) return;
  int n = idx >> 7, f = idx & (NF - 1);
  atom[idx] = emb[z[n] * NF + f];
}

// ---------------- edge embedding into SORTED slots ----------------
__global__ __launch_bounds__(256) void k_edge_embed(const int* __restrict__ ei,
                                                    const int* __restrict__ perm,
                                                    const float* __restrict__ pos,
                                                    int* __restrict__ iis, int* __restrict__ jjs,
                                                    float* __restrict__ ds, float* __restrict__ dirs){
  int s = blockIdx.x * 256 + threadIdx.x;
  if (s >= NE) return;
  int e = perm[s];
  int i = ei[e], j = ei[NE + e];
  float dx = pos[j*3+0] - pos[i*3+0];
  float dy = pos[j*3+1] - pos[i*3+1];
  float dz = pos[j*3+2] - pos[i*3+2];
  float d = sqrtf(dx*dx + dy*dy + dz*dz + 1e-12f);
  float inv = 1.0f / d;
  iis[s] = i; jjs[s] = j;
  ds[s] = d;
  dirs[s*3+0] = dx*inv; dirs[s*3+1] = dy*inv; dirs[s*3+2] = dz*inv;
}

// ---------------- fused node MLP (MFMA, 1 wave, r6-proven) ----------------
__global__ __launch_bounds__(64, 4) void k_node_mlp2(
    const float* __restrict__ atom,
    const u16* __restrict__ w1sw, const float* __restrict__ b1,
    const u16* __restrict__ w2sw, const float* __restrict__ b2,
    u32* __restrict__ hb)
{
  __shared__ __align__(16) u16 tileT[16][TPS];
  const int lane = threadIdx.x;
  const int q = lane >> 4, ln = lane & 15;
  const int n0 = blockIdx.x * 16;   // 625*16 = NN exactly

  floatx4 c1[8];
  #pragma unroll
  for (int tn = 0; tn < 8; tn++) c1[tn] = (floatx4){0,0,0,0};
  #pragma unroll
  for (int tk = 0; tk < 4; tk++){
    const float4 u0 = *(const float4*)&atom[(size_t)(n0+ln)*NF + tk*32 + q*8];
    const float4 u1 = *(const float4*)&atom[(size_t)(n0+ln)*NF + tk*32 + q*8 + 4];
    short8 a;
    a[0]=(short)f2b(u0.x); a[1]=(short)f2b(u0.y); a[2]=(short)f2b(u0.z); a[3]=(short)f2b(u0.w);
    a[4]=(short)f2b(u1.x); a[5]=(short)f2b(u1.y); a[6]=(short)f2b(u1.z); a[7]=(short)f2b(u1.w);
    #pragma unroll
    for (int tn = 0; tn < 8; tn++){
      short8 b = *(const short8*)(w1sw + (size_t)((tk*8 + tn)*64 + lane)*8);
      c1[tn] = __builtin_amdgcn_mfma_f32_16x16x32_bf16(a, b, c1[tn], 0, 0, 0);
    }
  }
  #pragma unroll
  for (int tn = 0; tn < 8; tn++){
    int n = tn*16 + ln;
    float bias = b1[n];
    #pragma unroll
    for (int r = 0; r < 4; r++)
      tileT[q*4 + r][n] = f2b(fast_silu(c1[tn][r] + bias));
  }

  floatx4 c2[8];
  #pragma unroll
  for (int tn = 0; tn < 8; tn++) c2[tn] = (floatx4){0,0,0,0};
  #pragma unroll
  for (int tk = 0; tk < 4; tk++){
    short8 a = *(const short8*)&tileT[ln][tk*32 + q*8];
    #pragma unroll
    for (int tn = 0; tn < 8; tn++){
      short8 b = *(const short8*)(w2sw + (size_t)((tk*8 + tn)*64 + lane)*8);
      c2[tn] = __builtin_amdgcn_mfma_f32_16x16x32_bf16(a, b, c2[tn], 0, 0, 0);
    }
  }
  float b2n[8];
  #pragma unroll
  for (int tn = 0; tn < 8; tn++) b2n[tn] = b2[tn*16 + ln];
  #pragma unroll
  for (int tn = 0; tn < 4; tn++){
    #pragma unroll
    for (int r = 0; r < 4; r++){
      float vl = c2[tn][r]   + b2n[tn];
      float vh = c2[tn+4][r] + b2n[tn+4];
      hb[(size_t)(n0 + q*4 + r)*64 + tn*16 + ln] = packbf(vl, vh);
    }
  }
}

// ---------------- MFMA edge kernel: r6 single-wave/single-tile body, partial STORES ----------------
// r6 sequencing (c2 then c1, silu'd c2 parked in regs) keeps peak acc = 64 regs, one LDS tile.
// The only change vs r6: atomicAdd -> plain stores of per-wave segment sums (wavebase indexing).
__global__ __launch_bounds__(64, 4) void k_edge_mfma(
    const int* __restrict__ iis, const int* __restrict__ jjs,
    const float* __restrict__ ds, const float* __restrict__ dirs,
    const u32* __restrict__ hb, const int* __restrict__ wavebase,
    const u16* __restrict__ mesw,
    const u16* __restrict__ w11sw, const u16* __restrict__ w12sw,
    const u16* __restrict__ w21sw, const u16* __restrict__ w22sw,
    const u32* __restrict__ forceb,
    float* __restrict__ msgpart, float* __restrict__ fpart)
{
  __shared__ __align__(16) u16 tileM[16][TPS];
  __shared__ int iiS[16];

  const int lane = threadIdx.x;
  const int q = lane >> 4, ln = lane & 15;
  const int w  = blockIdx.x;             // grid = NW exactly
  const int e0 = w * 16;

  if (lane < 16) iiS[lane] = iis[e0 + lane];
  const int base = wavebase[w];

  int iiR[4], jjR[4];
  float dirR[4][3];
  #pragma unroll
  for (int r = 0; r < 4; r++){
    int s = e0 + q*4 + r;
    iiR[r] = iis[s]; jjR[r] = jjs[s];
    dirR[r][0] = dirs[s*3+0]; dirR[r][1] = dirs[s*3+1]; dirR[r][2] = dirs[s*3+2];
  }

  // paired h gathers
  u32 hiw[4][4], hjw[4][4];
  #pragma unroll
  for (int r = 0; r < 4; r++)
    #pragma unroll
    for (int t4 = 0; t4 < 4; t4++){
      hiw[r][t4] = hb[(size_t)iiR[r]*64 + t4*16 + ln];
      hjw[r][t4] = hb[(size_t)jjR[r]*64 + t4*16 + ln];
    }

  // rbf A-fragment (K padded 20->32)
  float dA  = ds[e0 + ln];
  float fcA = (dA < CUT) ? 0.5f*(cosf((float)M_PI*dA*(1.0f/CUT)) + 1.0f) : 0.0f;
  short8 a_rbf;
  #pragma unroll
  for (int j = 0; j < 8; j++){
    int k = q*8 + j;
    float v = 0.f;
    if (k < NB){
      float t = (dA - CUT*(float)k/(float)(NB-1)) * ((float)NB/CUT);
      v = __expf(-t*t) * fcA;
    }
    a_rbf[j] = (short)f2b(v);
  }

  // me = rbf @ meW; msg = me*h_i*h_j -> tileM (bf16)
  #pragma unroll
  for (int tn = 0; tn < 8; tn++){
    short8 b = *(const short8*)(mesw + (size_t)(tn*64 + lane)*8);
    floatx4 c = {0.f,0.f,0.f,0.f};
    c = __builtin_amdgcn_mfma_f32_16x16x32_bf16(a_rbf, b, c, 0, 0, 0);
    int n = tn*16 + ln;
    int t4 = tn & 3;
    #pragma unroll
    for (int r = 0; r < 4; r++){
      float hi_ = (tn < 4) ? lo_bf(hiw[r][t4]) : hi_bf(hiw[r][t4]);
      float hj_ = (tn < 4) ? lo_bf(hjw[r][t4]) : hi_bf(hjw[r][t4]);
      tileM[q*4 + r][n] = f2b(c[r] * hi_ * hj_);
    }
  }

  // msg segment partials -> msgpart (plain stores)
  {
    int l = 0, seg = 0;
    for (int m = 1; m <= 16; m++){
      if (m == 16 || iiS[m] != iiS[seg]){
        for (int c = lane; c < NF; c += 64){
          float s = 0.f;
          for (int r = seg; r < m; r++) s += b2f_raw(tileM[r][c]);
          msgpart[(size_t)(base + l)*NF + c] = s;
        }
        l++; seg = m;
      }
    }
  }

  // c2 = msg @ w21 (held in regs as t2 after silu)
  floatx4 c2[8];
  #pragma unroll
  for (int tn = 0; tn < 8; tn++) c2[tn] = (floatx4){0,0,0,0};
  #pragma unroll
  for (int tk = 0; tk < 4; tk++){
    short8 a = *(const short8*)&tileM[ln][tk*32 + q*8];
    #pragma unroll
    for (int tn = 0; tn < 8; tn++){
      short8 b = *(const short8*)(w21sw + (size_t)((tk*8 + tn)*64 + lane)*8);
      c2[tn] = __builtin_amdgcn_mfma_f32_16x16x32_bf16(a, b, c2[tn], 0, 0, 0);
    }
  }
  // c1 = msg @ w11
  floatx4 c1[8];
  #pragma unroll
  for (int tn = 0; tn < 8; tn++) c1[tn] = (floatx4){0,0,0,0};
  #pragma unroll
  for (int tk = 0; tk < 4; tk++){
    short8 a = *(const short8*)&tileM[ln][tk*32 + q*8];
    #pragma unroll
    for (int tn = 0; tn < 8; tn++){
      short8 b = *(const short8*)(w11sw + (size_t)((tk*8 + tn)*64 + lane)*8);
      c1[tn] = __builtin_amdgcn_mfma_f32_16x16x32_bf16(a, b, c1[tn], 0, 0, 0);
    }
  }
  // t1 -> tileM ; t2 = silu(c2) stays in regs
  #pragma unroll
  for (int tn = 0; tn < 8; tn++){
    int n = tn*16 + ln;
    #pragma unroll
    for (int r = 0; r < 4; r++){
      tileM[q*4 + r][n] = f2b(fast_silu(c1[tn][r]));
      c2[tn][r] = fast_silu(c2[tn][r]);
    }
  }

  // g1 = t1 @ w12
  floatx4 g1[8];
  #pragma unroll
  for (int tn = 0; tn < 8; tn++) g1[tn] = (floatx4){0,0,0,0};
  #pragma unroll
  for (int tk = 0; tk < 4; tk++){
    short8 a = *(const short8*)&tileM[ln][tk*32 + q*8];
    #pragma unroll
    for (int tn = 0; tn < 8; tn++){
      short8 b = *(const short8*)(w12sw + (size_t)((tk*8 + tn)*64 + lane)*8);
      g1[tn] = __builtin_amdgcn_mfma_f32_16x16x32_bf16(a, b, g1[tn], 0, 0, 0);
    }
  }
  // t2 -> tileM
  #pragma unroll
  for (int tn = 0; tn < 8; tn++){
    int n = tn*16 + ln;
    #pragma unroll
    for (int r = 0; r < 4; r++) tileM[q*4 + r][n] = f2b(c2[tn][r]);
  }
  // g2 = t2 @ w22 (reuse c1)
  #pragma unroll
  for (int tn = 0; tn < 8; tn++) c1[tn] = (floatx4){0,0,0,0};
  #pragma unroll
  for (int tk = 0; tk < 4; tk++){
    short8 a = *(const short8*)&tileM[ln][tk*32 + q*8];
    #pragma unroll
    for (int tn = 0; tn < 8; tn++){
      short8 b = *(const short8*)(w22sw + (size_t)((tk*8 + tn)*64 + lane)*8);
      c1[tn] = __builtin_amdgcn_mfma_f32_16x16x32_bf16(a, b, c1[tn], 0, 0, 0);
    }
  }

  // three d-passes: tileM <- g1*dir + g2*force_old[j]; segment partials -> fpart
  for (int d = 0; d < 3; d++){
    u32 fjw[4][4];
    #pragma unroll
    for (int r = 0; r < 4; r++)
      #pragma unroll
      for (int t4 = 0; t4 < 4; t4++)
        fjw[r][t4] = forceb[((size_t)jjR[r]*3 + d)*64 + t4*16 + ln];
    #pragma unroll
    for (int tn = 0; tn < 8; tn++){
      int n = tn*16 + ln;
      int t4 = tn & 3;
      #pragma unroll
      for (int r = 0; r < 4; r++){
        float fj = (tn < 4) ? lo_bf(fjw[r][t4]) : hi_bf(fjw[r][t4]);
        tileM[q*4 + r][n] = f2b(g1[tn][r]*dirR[r][d] + c1[tn][r]*fj);
      }
    }
    int l = 0, seg = 0;
    for (int m = 1; m <= 16; m++){
      if (m == 16 || iiS[m] != iiS[seg]){
        for (int c = lane; c < NF; c += 64){
          float s = 0.f;
          for (int r = seg; r < m; r++) s += b2f_raw(tileM[r][c]);
          fpart[((size_t)(base + l)*3 + d)*NF + c] = s;
        }
        l++; seg = m;
      }
    }
  }
}

// ---------------- node update: aggregate partials + force update + forceb + eu term ----------------
// single wave, (64,2): register budget 256 — no spill risk (r9's (256,4) variant spilled).
__global__ __launch_bounds__(64, 2) void k_node_update(
    float* __restrict__ force,
    const float* __restrict__ msgpart, const float* __restrict__ fpart,
    const int* __restrict__ segptr,
    const u16* __restrict__ eusw, float* __restrict__ atom,
    u32* __restrict__ forceb)
{
  __shared__ __align__(16) u16 tile[16][TPS];
  __shared__ int spS[17];
  const int lane = threadIdx.x;
  const int q = lane >> 4, ln = lane & 15;
  const int n0 = blockIdx.x * 16;   // 625*16 = NN exactly
  if (lane < 17) spS[lane] = segptr[n0 + lane];

  // atom += per-node msg aggregation (exclusive rows, plain r-m-w)
  #pragma unroll 2
  for (int m = 0; m < 16; m++){
    int a = spS[m], b = spS[m+1];
    float s0 = 0.f, s1 = 0.f;
    for (int t = a; t < b; t++){
      s0 += msgpart[(size_t)t*NF + lane];
      s1 += msgpart[(size_t)t*NF + lane + 64];
    }
    size_t idx = (size_t)(n0+m)*NF + lane;
    atom[idx]    += s0;
    atom[idx+64] += s1;
  }

  floatx4 sacc[8];
  #pragma unroll
  for (int tn = 0; tn < 8; tn++) sacc[tn] = (floatx4){0,0,0,0};

  for (int d = 0; d < 3; d++){
    #pragma unroll 2
    for (int m = 0; m < 16; m++){
      int a = spS[m], b = spS[m+1];
      size_t idx = ((size_t)(n0+m)*3 + d)*NF + lane;
      float v0 = force[idx], v1 = force[idx+64];
      for (int t = a; t < b; t++){
        v0 += fpart[((size_t)t*3 + d)*NF + lane];
        v1 += fpart[((size_t)t*3 + d)*NF + lane + 64];
      }
      force[idx] = v0; force[idx+64] = v1;
      forceb[((size_t)(n0+m)*3 + d)*64 + lane] = packbf(v0, v1);
      tile[m][lane]    = f2b(v0);
      tile[m][lane+64] = f2b(v1);
    }
    // t_d = force_d @ euW
    floatx4 c[8];
    #pragma unroll
    for (int tn = 0; tn < 8; tn++) c[tn] = (floatx4){0,0,0,0};
    #pragma unroll
    for (int tk = 0; tk < 4; tk++){
      short8 a = *(const short8*)&tile[ln][tk*32 + q*8];
      #pragma unroll
      for (int tn = 0; tn < 8; tn++){
        short8 b = *(const short8*)(eusw + (size_t)((tk*8 + tn)*64 + lane)*8);
        c[tn] = __builtin_amdgcn_mfma_f32_16x16x32_bf16(a, b, c[tn], 0, 0, 0);
      }
    }
    #pragma unroll
    for (int tn = 0; tn < 8; tn++){
      int n = tn*16 + ln;
      #pragma unroll
      for (int r = 0; r < 4; r++)
        sacc[tn][r] += b2f_raw(tile[q*4 + r][n]) * c[tn][r];
    }
  }
  // atom += eu term (C-layout, exclusive rows)
  #pragma unroll
  for (int tn = 0; tn < 8; tn++){
    int n = tn*16 + ln;
    #pragma unroll
    for (int r = 0; r < 4; r++){
      size_t idx = (size_t)(n0 + q*4 + r)*NF + n;
      atom[idx] += sacc[tn][r];
    }
  }
}

// ---------------- write out ----------------
__global__ __launch_bounds__(256) void k_writeout(const float* __restrict__ atom,
                                                  const float* __restrict__ force,
                                                  void* __restrict__ out,
                                                  const int* __restrict__ flag){
  int idx = blockIdx.x * 256 + threadIdx.x;
  const int na = NN * NF;
  const int tot = na + NN * 3 * NF;
  if (idx >= tot) return;
  float v = (idx < na) ? atom[idx] : force[idx - na];
  if (*flag) ((__hip_bfloat16*)out)[idx] = __float2bfloat16(v);
  else       ((float*)out)[idx] = v;
}

extern "C" void kernel_launch(void* const* d_in, const int* in_sizes, int n_in,
                              void* d_out, int out_size, void* d_ws, size_t ws_size,
                              hipStream_t stream){
  const int* z    = (const int*)d_in[0];
  const void* pos = d_in[1];
  // d_in[2] cell, d_in[3] batch: numerically dead (sym == I)
  const int* ei   = (const int*)d_in[4];
  const void* emb   = d_in[5];
  const void* mnpW1 = d_in[6];
  const void* mnpb1 = d_in[7];
  const void* mnpW2 = d_in[8];
  const void* mnpb2 = d_in[9];
  const void* meW   = d_in[10];
  const void* em1W1 = d_in[11];
  const void* em1W2 = d_in[12];
  const void* em2W1 = d_in[13];
  const void* em2W2 = d_in[14];
  const void* euW   = d_in[15];

  float* base  = (float*)d_ws;
  int*   flag  = (int*)d_ws;                  // 4 floats reserved
  float* atom   = base + 4;                   // NN*NF
  float* force  = atom   + NN*NF;             // NN*3*NF
  u32*   forceb = (u32*)(force + (size_t)NN*3*NF);   // NN*3*64
  int*   count  = (int*)(forceb + (size_t)NN*3*64);  // NN
  // memset zeroes force + forceb + count (contiguous)
  float* ds    = (float*)(count + NN);
  float* dirs  = ds + NE;
  float* posf  = dirs + 3*NE;
  float* embf  = posf + NN*3;
  float* b1f   = embf + 119*NF;               // 3*NF
  float* b2f_  = b1f + 3*NF;                  // 3*NF
  u32*   hb    = (u32*)(b2f_ + 3*NF);         // NN*64
  u16*   mesw  = (u16*)(hb + (size_t)NN*64);  // 3*4096
  u16*   w11sw = mesw  + 3*4096;
  u16*   w12sw = w11sw + 3*16384;
  u16*   w21sw = w12sw + 3*16384;
  u16*   w22sw = w21sw + 3*16384;
  u16*   w1sw  = w22sw + 3*16384;
  u16*   w2sw  = w1sw  + 3*16384;
  u16*   eusw  = w2sw  + 3*16384;
  int* rowptr  = (int*)(eusw + 3*16384);      // NN+1
  int* cursor  = rowptr + NN + 1;
  int* perm    = cursor + NN;                 // NE
  int* iis     = perm + NE;
  int* jjs     = iis + NE;
  int* wcnt    = jjs + NE;                    // NW
  int* wavebase= wcnt + NW;                   // NW+1
  int* ncnt    = wavebase + NW + 1;           // NN
  int* segptr  = ncnt + NN;                   // NN+1
  float* msgpart = (float*)(segptr + NN + 1); // MAXSEG*NF
  float* fpart   = msgpart + (size_t)MAXSEG*NF;  // MAXSEG*3*NF

  k_detect<<<1, 256, 0, stream>>>(meW, 3*NB*NF, flag);

  // zero force + forceb + count in one shot
  hipMemsetAsync(force, 0, ((size_t)NN*3*NF + (size_t)NN*3*64 + NN)*4, stream);

  CvtArgs ca;
  ca.src[0]=pos;   ca.dst[0]=posf; ca.n[0]=NN*3;
  ca.src[1]=emb;   ca.dst[1]=embf; ca.n[1]=119*NF;
  ca.src[2]=mnpb1; ca.dst[2]=b1f;  ca.n[2]=3*NF;
  ca.src[3]=mnpb2; ca.dst[3]=b2f_; ca.n[3]=3*NF;
  k_cvt4<<<dim3(60,4), 256, 0, stream>>>(ca, flag);

  SwzArgs sa;
  sa.src[0]=em1W1; sa.dst[0]=w11sw;
  sa.src[1]=em1W2; sa.dst[1]=w12sw;
  sa.src[2]=em2W1; sa.dst[2]=w21sw;
  sa.src[3]=em2W2; sa.dst[3]=w22sw;
  sa.src[4]=mnpW1; sa.dst[4]=w1sw;
  sa.src[5]=mnpW2; sa.dst[5]=w2sw;
  sa.src[6]=euW;   sa.dst[6]=eusw;
  k_swz7 <<<dim3(192,7), 256, 0, stream>>>(sa, flag);
  k_swzme<<<(3*4096+255)/256, 256, 0, stream>>>(meW, mesw, flag);

  k_hist      <<<(NE+255)/256, 256, 0, stream>>>(ei, count);
  k_scan      <<<1, 256, 0, stream>>>(count, rowptr, cursor);
  k_scatter   <<<(NE+255)/256, 256, 0, stream>>>(ei, cursor, perm);
  k_edge_embed<<<(NE+255)/256, 256, 0, stream>>>(ei, perm, posf, iis, jjs, ds, dirs);
  k_wavecnt   <<<(NW+255)/256, 256, 0, stream>>>(iis, wcnt);
  k_scan_g    <<<1, 256, 0, stream>>>(wcnt, wavebase, NW);
  k_nodesegcnt<<<(NN+255)/256, 256, 0, stream>>>(rowptr, ncnt);
  k_scan_g    <<<1, 256, 0, stream>>>(ncnt, segptr, NN);
  k_init_atom <<<(NN*NF+255)/256, 256, 0, stream>>>(z, embf, atom);

  for (int l = 0; l < 3; l++){
    k_node_mlp2<<<NN/16, 64, 0, stream>>>(atom,
        w1sw + (size_t)l*16384, b1f + (size_t)l*NF,
        w2sw + (size_t)l*16384, b2f_ + (size_t)l*NF, hb);
    k_edge_mfma<<<NW, 64, 0, stream>>>(iis, jjs, ds, dirs, hb, wavebase,
        mesw  + (size_t)l*4096,
        w11sw + (size_t)l*16384, w12sw + (size_t)l*16384,
        w21sw + (size_t)l*16384, w22sw + (size_t)l*16384,
        forceb, msgpart, fpart);
    k_node_update<<<NN/16, 64, 0, stream>>>(force, msgpart, fpart,
        segptr, eusw + (size_t)l*16384, atom, forceb);
  }

  k_writeout<<<(NN*NF + NN*3*NF + 255)/256, 256, 0, stream>>>(atom, force, d_out, flag);
}

// Round 11
// 717.242 us; speedup vs baseline: 1.2902x; 1.1174x over previous
//
#include <hip/hip_runtime.h>
#include <hip/hip_bf16.h>
#include <math.h>

#define NN 10000
#define NE 160000
#define NF 128
#define NB 20
#define CUT 5.0f
#define TPS 136   // u16 tile row stride

typedef __attribute__((ext_vector_type(8))) short short8;
typedef __attribute__((ext_vector_type(4))) float floatx4;
typedef unsigned short u16;
typedef unsigned int u32;

__device__ __forceinline__ u16 f2b(float x){
  union { __hip_bfloat16 b; u16 u; } cv;
  cv.b = __float2bfloat16(x);
  return cv.u;
}
__device__ __forceinline__ float b2f_raw(u16 x){ return __uint_as_float((u32)x << 16); }
__device__ __forceinline__ float lo_bf(u32 w){ return __uint_as_float(w << 16); }
__device__ __forceinline__ float hi_bf(u32 w){ return __uint_as_float(w & 0xFFFF0000u); }
__device__ __forceinline__ u32 packbf(float lo, float hi){
  return ((u32)f2b(hi) << 16) | (u32)f2b(lo);
}
__device__ __forceinline__ float fast_silu(float v){
  return v * __builtin_amdgcn_rcpf(1.f + __expf(-v));
}
__device__ __forceinline__ float rdf(const void* p, size_t i, int isb){
  return isb ? __bfloat162float(((const __hip_bfloat16*)p)[i]) : ((const float*)p)[i];
}

// ---------------- dtype detector: 1=bf16, 0=fp32 ----------------
__global__ __launch_bounds__(256) void k_detect(const void* __restrict__ w, int nelem,
                                                int* __restrict__ flag){
  __shared__ int cnt;
  if (threadIdx.x == 0) cnt = 0;
  __syncthreads();
  const u16* hw = (const u16*)w;
  int local = 0;
  for (int k = threadIdx.x; k < nelem; k += 256){
    u16 h = hw[k];
    int e = (h >> 7) & 0xFF;
    if ((h & 0x7FFF) == 0 || (e >= 103 && e <= 130)) local++;
  }
  atomicAdd(&cnt, local);
  __syncthreads();
  if (threadIdx.x == 0) *flag = (cnt >= (nelem * 9) / 10) ? 1 : 0;
}

// ---------------- fused convert-to-fp32 (4 tensors) ----------------
struct CvtArgs { const void* src[4]; float* dst[4]; int n[4]; };
__global__ __launch_bounds__(256) void k_cvt4(CvtArgs a, const int* __restrict__ flag){
  int y = blockIdx.y;
  int isb = *flag;
  const void* s = a.src[y]; float* d = a.dst[y]; int n = a.n[y];
  for (int i = blockIdx.x*256 + threadIdx.x; i < n; i += gridDim.x*256)
    d[i] = rdf(s, i, isb);
}

// ---------------- fused weight swizzle (7 128x128 matrices) ----------------
struct SwzArgs { const void* src[7]; u16* dst[7]; };
__global__ __launch_bounds__(256) void k_swz7(SwzArgs a, const int* __restrict__ flag){
  int y = blockIdx.y;
  int isb = *flag;
  const void* s = a.src[y]; u16* d = a.dst[y];
  int idx = blockIdx.x*256 + threadIdx.x;        // 192*256 = 3*16384
  int l = idx >> 14, rem = idx & 16383;
  int j = rem & 7, lane = (rem >> 3) & 63, tn = (rem >> 9) & 7, tk = rem >> 12;
  int k = tk*32 + ((lane >> 4) & 3)*8 + j, n = tn*16 + (lane & 15);
  d[idx] = f2b(rdf(s, (size_t)l*16384 + k*NF + n, isb));
}
__global__ __launch_bounds__(256) void k_swzme(const void* __restrict__ W, u16* __restrict__ out,
                                               const int* __restrict__ flag){
  int idx = blockIdx.x*256 + threadIdx.x;     // 3*4096
  if (idx >= 3*4096) return;
  int isb = *flag;
  int l = idx >> 12, rem = idx & 4095;
  int j = rem & 7, lane = (rem >> 3) & 63, tn = rem >> 9;
  int k = ((lane >> 4) & 3)*8 + j, n = tn*16 + (lane & 15);
  out[idx] = (k < NB) ? f2b(rdf(W, (size_t)l*NB*NF + k*NF + n, isb)) : (u16)0;
}

// ---------------- counting sort of edges by destination i ----------------
__global__ __launch_bounds__(256) void k_hist(const int* __restrict__ ei, int* __restrict__ count){
  int e = blockIdx.x*256 + threadIdx.x;
  if (e < NE) atomicAdd(&count[ei[e]], 1);
}
__global__ __launch_bounds__(256) void k_scan(const int* __restrict__ count,
                                              int* __restrict__ rowptr, int* __restrict__ cursor){
  __shared__ int part[256];
  const int CH = (NN + 255) / 256;
  int t = threadIdx.x;
  int base = t * CH;
  int s = 0;
  for (int k = 0; k < CH; k++){ int i = base + k; if (i < NN) s += count[i]; }
  part[t] = s;
  __syncthreads();
  for (int off = 1; off < 256; off <<= 1){
    int v = (t >= off) ? part[t - off] : 0;
    __syncthreads();
    part[t] += v;
    __syncthreads();
  }
  int run = (t == 0) ? 0 : part[t - 1];
  for (int k = 0; k < CH; k++){
    int i = base + k;
    if (i < NN){ rowptr[i] = run; cursor[i] = run; run += count[i]; }
  }
  if (t == 255) rowptr[NN] = run;
}
__global__ __launch_bounds__(256) void k_scatter(const int* __restrict__ ei,
                                                 int* __restrict__ cursor, int* __restrict__ perm){
  int e = blockIdx.x*256 + threadIdx.x;
  if (e >= NE) return;
  int pos = atomicAdd(&cursor[ei[e]], 1);
  perm[pos] = e;
}

// ---------------- init atom ----------------
__global__ __launch_bounds__(256) void k_init_atom(const int* __restrict__ z,
                                                   const float* __restrict__ emb,
                                                   float* __restrict__ atom){
  int idx = blockIdx.x * 256 + threadIdx.x;
  if (idx >= NN * NF) return;
  int n = idx >> 7, f = idx & (NF - 1);
  atom[idx] = emb[z[n] * NF + f];
}

// ---------------- edge embedding into SORTED slots ----------------
__global__ __launch_bounds__(256) void k_edge_embed(const int* __restrict__ ei,
                                                    const int* __restrict__ perm,
                                                    const float* __restrict__ pos,
                                                    int* __restrict__ iis, int* __restrict__ jjs,
                                                    float* __restrict__ ds, float* __restrict__ dirs){
  int s = blockIdx.x * 256 + threadIdx.x;
  if (s >= NE) return;
  int e = perm[s];
  int i = ei[e], j = ei[NE + e];
  float dx = pos[j*3+0] - pos[i*3+0];
  float dy = pos[j*3+1] - pos[i*3+1];
  float dz = pos[j*3+2] - pos[i*3+2];
  float d = sqrtf(dx*dx + dy*dy + dz*dz + 1e-12f);
  float inv = 1.0f / d;
  iis[s] = i; jjs[s] = j;
  ds[s] = d;
  dirs[s*3+0] = dx*inv; dirs[s*3+1] = dy*inv; dirs[s*3+2] = dz*inv;
}

// ---------------- node MLP (MFMA, 1 wave) — first layer only ----------------
__global__ __launch_bounds__(64, 4) void k_node_mlp2(
    const float* __restrict__ atom,
    const u16* __restrict__ w1sw, const float* __restrict__ b1,
    const u16* __restrict__ w2sw, const float* __restrict__ b2,
    u32* __restrict__ hb)
{
  __shared__ __align__(16) u16 tileT[16][TPS];
  const int lane = threadIdx.x;
  const int q = lane >> 4, ln = lane & 15;
  const int n0 = blockIdx.x * 16;   // 625*16 = NN exactly

  floatx4 c1[8];
  #pragma unroll
  for (int tn = 0; tn < 8; tn++) c1[tn] = (floatx4){0,0,0,0};
  #pragma unroll
  for (int tk = 0; tk < 4; tk++){
    const float4 u0 = *(const float4*)&atom[(size_t)(n0+ln)*NF + tk*32 + q*8];
    const float4 u1 = *(const float4*)&atom[(size_t)(n0+ln)*NF + tk*32 + q*8 + 4];
    short8 a;
    a[0]=(short)f2b(u0.x); a[1]=(short)f2b(u0.y); a[2]=(short)f2b(u0.z); a[3]=(short)f2b(u0.w);
    a[4]=(short)f2b(u1.x); a[5]=(short)f2b(u1.y); a[6]=(short)f2b(u1.z); a[7]=(short)f2b(u1.w);
    #pragma unroll
    for (int tn = 0; tn < 8; tn++){
      short8 b = *(const short8*)(w1sw + (size_t)((tk*8 + tn)*64 + lane)*8);
      c1[tn] = __builtin_amdgcn_mfma_f32_16x16x32_bf16(a, b, c1[tn], 0, 0, 0);
    }
  }
  #pragma unroll
  for (int tn = 0; tn < 8; tn++){
    int n = tn*16 + ln;
    float bias = b1[n];
    #pragma unroll
    for (int r = 0; r < 4; r++)
      tileT[q*4 + r][n] = f2b(fast_silu(c1[tn][r] + bias));
  }

  floatx4 c2[8];
  #pragma unroll
  for (int tn = 0; tn < 8; tn++) c2[tn] = (floatx4){0,0,0,0};
  #pragma unroll
  for (int tk = 0; tk < 4; tk++){
    short8 a = *(const short8*)&tileT[ln][tk*32 + q*8];
    #pragma unroll
    for (int tn = 0; tn < 8; tn++){
      short8 b = *(const short8*)(w2sw + (size_t)((tk*8 + tn)*64 + lane)*8);
      c2[tn] = __builtin_amdgcn_mfma_f32_16x16x32_bf16(a, b, c2[tn], 0, 0, 0);
    }
  }
  float b2n[8];
  #pragma unroll
  for (int tn = 0; tn < 8; tn++) b2n[tn] = b2[tn*16 + ln];
  #pragma unroll
  for (int tn = 0; tn < 4; tn++){
    #pragma unroll
    for (int r = 0; r < 4; r++){
      float vl = c2[tn][r]   + b2n[tn];
      float vh = c2[tn+4][r] + b2n[tn+4];
      hb[(size_t)(n0 + q*4 + r)*64 + tn*16 + ln] = packbf(vl, vh);
    }
  }
}

// ---------------- MFMA edge kernel: r6 proven body (1 wave, atomics) ----------------
__global__ __launch_bounds__(64, 4) void k_edge_mfma(
    const int* __restrict__ iis, const int* __restrict__ jjs,
    const float* __restrict__ ds, const float* __restrict__ dirs,
    const u32* __restrict__ hb,
    const u16* __restrict__ mesw,
    const u16* __restrict__ w11sw, const u16* __restrict__ w12sw,
    const u16* __restrict__ w21sw, const u16* __restrict__ w22sw,
    float* __restrict__ atom, const u32* __restrict__ forceb, float* __restrict__ fdelta)
{
  __shared__ __align__(16) u16 tileM[16][TPS];
  __shared__ int iiS[16];

  const int lane = threadIdx.x;
  const int q = lane >> 4, ln = lane & 15;
  const int e0 = blockIdx.x * 16;   // grid = NE/16 exactly

  if (lane < 16) iiS[lane] = iis[e0 + lane];

  int iiR[4], jjR[4];
  float dirR[4][3];
  #pragma unroll
  for (int r = 0; r < 4; r++){
    int s = e0 + q*4 + r;
    iiR[r] = iis[s]; jjR[r] = jjs[s];
    dirR[r][0] = dirs[s*3+0]; dirR[r][1] = dirs[s*3+1]; dirR[r][2] = dirs[s*3+2];
  }

  // paired h gathers
  u32 hiw[4][4], hjw[4][4];
  #pragma unroll
  for (int r = 0; r < 4; r++)
    #pragma unroll
    for (int t4 = 0; t4 < 4; t4++){
      hiw[r][t4] = hb[(size_t)iiR[r]*64 + t4*16 + ln];
      hjw[r][t4] = hb[(size_t)jjR[r]*64 + t4*16 + ln];
    }

  // rbf A-fragment (K padded 20->32)
  float dA  = ds[e0 + ln];
  float fcA = (dA < CUT) ? 0.5f*(cosf((float)M_PI*dA*(1.0f/CUT)) + 1.0f) : 0.0f;
  short8 a_rbf;
  #pragma unroll
  for (int j = 0; j < 8; j++){
    int k = q*8 + j;
    float v = 0.f;
    if (k < NB){
      float t = (dA - CUT*(float)k/(float)(NB-1)) * ((float)NB/CUT);
      v = __expf(-t*t) * fcA;
    }
    a_rbf[j] = (short)f2b(v);
  }

  // me = rbf @ meW; msg = me*h_i*h_j -> tileM (bf16)
  #pragma unroll
  for (int tn = 0; tn < 8; tn++){
    short8 b = *(const short8*)(mesw + (size_t)(tn*64 + lane)*8);
    floatx4 c = {0.f,0.f,0.f,0.f};
    c = __builtin_amdgcn_mfma_f32_16x16x32_bf16(a_rbf, b, c, 0, 0, 0);
    int n = tn*16 + ln;
    int t4 = tn & 3;
    #pragma unroll
    for (int r = 0; r < 4; r++){
      float hi_ = (tn < 4) ? lo_bf(hiw[r][t4]) : hi_bf(hiw[r][t4]);
      float hj_ = (tn < 4) ? lo_bf(hjw[r][t4]) : hi_bf(hjw[r][t4]);
      tileM[q*4 + r][n] = f2b(c[r] * hi_ * hj_);
    }
  }

  // atom segment flush from tileM (atomics — proven cheap after sorting)
  {
    int seg = 0;
    for (int m = 1; m <= 16; m++){
      if (m == 16 || iiS[m] != iiS[seg]){
        int ii = iiS[seg];
        for (int c = lane; c < NF; c += 64){
          float s = 0.f;
          for (int r = seg; r < m; r++) s += b2f_raw(tileM[r][c]);
          atomicAdd(&atom[(size_t)ii*NF + c], s);
        }
        seg = m;
      }
    }
  }

  // c2 = msg @ w21 (held in regs as t2 after silu)
  floatx4 c2[8];
  #pragma unroll
  for (int tn = 0; tn < 8; tn++) c2[tn] = (floatx4){0,0,0,0};
  #pragma unroll
  for (int tk = 0; tk < 4; tk++){
    short8 a = *(const short8*)&tileM[ln][tk*32 + q*8];
    #pragma unroll
    for (int tn = 0; tn < 8; tn++){
      short8 b = *(const short8*)(w21sw + (size_t)((tk*8 + tn)*64 + lane)*8);
      c2[tn] = __builtin_amdgcn_mfma_f32_16x16x32_bf16(a, b, c2[tn], 0, 0, 0);
    }
  }
  // c1 = msg @ w11
  floatx4 c1[8];
  #pragma unroll
  for (int tn = 0; tn < 8; tn++) c1[tn] = (floatx4){0,0,0,0};
  #pragma unroll
  for (int tk = 0; tk < 4; tk++){
    short8 a = *(const short8*)&tileM[ln][tk*32 + q*8];
    #pragma unroll
    for (int tn = 0; tn < 8; tn++){
      short8 b = *(const short8*)(w11sw + (size_t)((tk*8 + tn)*64 + lane)*8);
      c1[tn] = __builtin_amdgcn_mfma_f32_16x16x32_bf16(a, b, c1[tn], 0, 0, 0);
    }
  }
  // t1 -> tileM ; t2 = silu(c2) stays in regs
  #pragma unroll
  for (int tn = 0; tn < 8; tn++){
    int n = tn*16 + ln;
    #pragma unroll
    for (int r = 0; r < 4; r++){
      tileM[q*4 + r][n] = f2b(fast_silu(c1[tn][r]));
      c2[tn][r] = fast_silu(c2[tn][r]);
    }
  }

  // g1 = t1 @ w12
  floatx4 g1[8];
  #pragma unroll
  for (int tn = 0; tn < 8; tn++) g1[tn] = (floatx4){0,0,0,0};
  #pragma unroll
  for (int tk = 0; tk < 4; tk++){
    short8 a = *(const short8*)&tileM[ln][tk*32 + q*8];
    #pragma unroll
    for (int tn = 0; tn < 8; tn++){
      short8 b = *(const short8*)(w12sw + (size_t)((tk*8 + tn)*64 + lane)*8);
      g1[tn] = __builtin_amdgcn_mfma_f32_16x16x32_bf16(a, b, g1[tn], 0, 0, 0);
    }
  }
  // t2 -> tileM
  #pragma unroll
  for (int tn = 0; tn < 8; tn++){
    int n = tn*16 + ln;
    #pragma unroll
    for (int r = 0; r < 4; r++) tileM[q*4 + r][n] = f2b(c2[tn][r]);
  }
  // g2 = t2 @ w22 (reuse c1)
  #pragma unroll
  for (int tn = 0; tn < 8; tn++) c1[tn] = (floatx4){0,0,0,0};
  #pragma unroll
  for (int tk = 0; tk < 4; tk++){
    short8 a = *(const short8*)&tileM[ln][tk*32 + q*8];
    #pragma unroll
    for (int tn = 0; tn < 8; tn++){
      short8 b = *(const short8*)(w22sw + (size_t)((tk*8 + tn)*64 + lane)*8);
      c1[tn] = __builtin_amdgcn_mfma_f32_16x16x32_bf16(a, b, c1[tn], 0, 0, 0);
    }
  }

  // three d-passes: tileM <- g1*dir + g2*force_old[j]; segment flush into fdelta
  for (int d = 0; d < 3; d++){
    u32 fjw[4][4];
    #pragma unroll
    for (int r = 0; r < 4; r++)
      #pragma unroll
      for (int t4 = 0; t4 < 4; t4++)
        fjw[r][t4] = forceb[((size_t)jjR[r]*3 + d)*64 + t4*16 + ln];
    #pragma unroll
    for (int tn = 0; tn < 8; tn++){
      int n = tn*16 + ln;
      int t4 = tn & 3;
      #pragma unroll
      for (int r = 0; r < 4; r++){
        float fj = (tn < 4) ? lo_bf(fjw[r][t4]) : hi_bf(fjw[r][t4]);
        tileM[q*4 + r][n] = f2b(g1[tn][r]*dirR[r][d] + c1[tn][r]*fj);
      }
    }
    int seg = 0;
    for (int m = 1; m <= 16; m++){
      if (m == 16 || iiS[m] != iiS[seg]){
        int ii = iiS[seg];
        for (int c = lane; c < NF; c += 64){
          float s = 0.f;
          for (int r = seg; r < m; r++) s += b2f_raw(tileM[r][c]);
          atomicAdd(&fdelta[((size_t)ii*3 + d)*NF + c], s);
        }
        seg = m;
      }
    }
  }
}

// ---------------- fused node kernel: update(l) + MLP(l+1) ----------------
// Single wave, (64,2): 256-reg budget, no spill. Phase 1: force+=fdelta (re-zero),
// forceb mirror, eu MFMA -> atom. Phase 2 (if do_mlp): next layer's h from updated atom.
__global__ __launch_bounds__(64, 2) void k_node_fused(
    float* __restrict__ force, float* __restrict__ fdelta,
    const u16* __restrict__ eusw, float* __restrict__ atom,
    u32* __restrict__ forceb,
    const u16* __restrict__ w1sw, const float* __restrict__ b1,
    const u16* __restrict__ w2sw, const float* __restrict__ b2,
    u32* __restrict__ hb, int do_mlp)
{
  __shared__ __align__(16) u16 tile[16][TPS];
  const int lane = threadIdx.x;
  const int q = lane >> 4, ln = lane & 15;
  const int n0 = blockIdx.x * 16;   // 625*16 = NN exactly

  floatx4 sacc[8];
  #pragma unroll
  for (int tn = 0; tn < 8; tn++) sacc[tn] = (floatx4){0,0,0,0};

  for (int d = 0; d < 3; d++){
    #pragma unroll
    for (int m = 0; m < 16; m++){
      size_t idx = ((size_t)(n0+m)*3 + d)*NF + lane;
      float v0 = force[idx]    + fdelta[idx];
      float v1 = force[idx+64] + fdelta[idx+64];
      force[idx] = v0; force[idx+64] = v1;
      fdelta[idx] = 0.f; fdelta[idx+64] = 0.f;
      forceb[((size_t)(n0+m)*3 + d)*64 + lane] = packbf(v0, v1);
      tile[m][lane]    = f2b(v0);
      tile[m][lane+64] = f2b(v1);
    }
    floatx4 c[8];
    #pragma unroll
    for (int tn = 0; tn < 8; tn++) c[tn] = (floatx4){0,0,0,0};
    #pragma unroll
    for (int tk = 0; tk < 4; tk++){
      short8 a = *(const short8*)&tile[ln][tk*32 + q*8];
      #pragma unroll
      for (int tn = 0; tn < 8; tn++){
        short8 b = *(const short8*)(eusw + (size_t)((tk*8 + tn)*64 + lane)*8);
        c[tn] = __builtin_amdgcn_mfma_f32_16x16x32_bf16(a, b, c[tn], 0, 0, 0);
      }
    }
    #pragma unroll
    for (int tn = 0; tn < 8; tn++){
      int n = tn*16 + ln;
      #pragma unroll
      for (int r = 0; r < 4; r++)
        sacc[tn][r] += b2f_raw(tile[q*4 + r][n]) * c[tn][r];
    }
  }
  // atom += eu term (C-layout, exclusive rows) — keep values in regs for phase 2
  float anew[8][4];
  #pragma unroll
  for (int tn = 0; tn < 8; tn++){
    int n = tn*16 + ln;
    #pragma unroll
    for (int r = 0; r < 4; r++){
      size_t idx = (size_t)(n0 + q*4 + r)*NF + n;
      float v = atom[idx] + sacc[tn][r];
      atom[idx] = v;
      anew[tn][r] = v;
    }
  }
  if (!do_mlp) return;

  // ---- phase 2: h(l+1) = (silu(atom@W1+b1))@W2+b2 ----
  // stage updated atom (C-layout regs) into bf16 tile, read back as A-frags
  #pragma unroll
  for (int tn = 0; tn < 8; tn++){
    int n = tn*16 + ln;
    #pragma unroll
    for (int r = 0; r < 4; r++) tile[q*4 + r][n] = f2b(anew[tn][r]);
  }
  floatx4 c1[8];
  #pragma unroll
  for (int tn = 0; tn < 8; tn++) c1[tn] = (floatx4){0,0,0,0};
  #pragma unroll
  for (int tk = 0; tk < 4; tk++){
    short8 a = *(const short8*)&tile[ln][tk*32 + q*8];
    #pragma unroll
    for (int tn = 0; tn < 8; tn++){
      short8 b = *(const short8*)(w1sw + (size_t)((tk*8 + tn)*64 + lane)*8);
      c1[tn] = __builtin_amdgcn_mfma_f32_16x16x32_bf16(a, b, c1[tn], 0, 0, 0);
    }
  }
  #pragma unroll
  for (int tn = 0; tn < 8; tn++){
    int n = tn*16 + ln;
    float bias = b1[n];
    #pragma unroll
    for (int r = 0; r < 4; r++)
      tile[q*4 + r][n] = f2b(fast_silu(c1[tn][r] + bias));
  }
  floatx4 c2[8];
  #pragma unroll
  for (int tn = 0; tn < 8; tn++) c2[tn] = (floatx4){0,0,0,0};
  #pragma unroll
  for (int tk = 0; tk < 4; tk++){
    short8 a = *(const short8*)&tile[ln][tk*32 + q*8];
    #pragma unroll
    for (int tn = 0; tn < 8; tn++){
      short8 b = *(const short8*)(w2sw + (size_t)((tk*8 + tn)*64 + lane)*8);
      c2[tn] = __builtin_amdgcn_mfma_f32_16x16x32_bf16(a, b, c2[tn], 0, 0, 0);
    }
  }
  float b2n[8];
  #pragma unroll
  for (int tn = 0; tn < 8; tn++) b2n[tn] = b2[tn*16 + ln];
  #pragma unroll
  for (int tn = 0; tn < 4; tn++){
    #pragma unroll
    for (int r = 0; r < 4; r++){
      float vl = c2[tn][r]   + b2n[tn];
      float vh = c2[tn+4][r] + b2n[tn+4];
      hb[(size_t)(n0 + q*4 + r)*64 + tn*16 + ln] = packbf(vl, vh);
    }
  }
}

// ---------------- write out ----------------
__global__ __launch_bounds__(256) void k_writeout(const float* __restrict__ atom,
                                                  const float* __restrict__ force,
                                                  void* __restrict__ out,
                                                  const int* __restrict__ flag){
  int idx = blockIdx.x * 256 + threadIdx.x;
  const int na = NN * NF;
  const int tot = na + NN * 3 * NF;
  if (idx >= tot) return;
  float v = (idx < na) ? atom[idx] : force[idx - na];
  if (*flag) ((__hip_bfloat16*)out)[idx] = __float2bfloat16(v);
  else       ((float*)out)[idx] = v;
}

extern "C" void kernel_launch(void* const* d_in, const int* in_sizes, int n_in,
                              void* d_out, int out_size, void* d_ws, size_t ws_size,
                              hipStream_t stream){
  const int* z    = (const int*)d_in[0];
  const void* pos = d_in[1];
  // d_in[2] cell, d_in[3] batch: numerically dead (sym == I)
  const int* ei   = (const int*)d_in[4];
  const void* emb   = d_in[5];
  const void* mnpW1 = d_in[6];
  const void* mnpb1 = d_in[7];
  const void* mnpW2 = d_in[8];
  const void* mnpb2 = d_in[9];
  const void* meW   = d_in[10];
  const void* em1W1 = d_in[11];
  const void* em1W2 = d_in[12];
  const void* em2W1 = d_in[13];
  const void* em2W2 = d_in[14];
  const void* euW   = d_in[15];

  float* base  = (float*)d_ws;
  int*   flag  = (int*)d_ws;                  // 4 floats reserved
  float* atom   = base + 4;                   // NN*NF
  float* force  = atom   + NN*NF;             // NN*3*NF
  float* fdelta = force  + (size_t)NN*3*NF;   // NN*3*NF
  u32*   forceb = (u32*)(fdelta + (size_t)NN*3*NF);  // NN*3*64
  int*   count  = (int*)(forceb + (size_t)NN*3*64);  // NN
  // single memset zeroes force, fdelta, forceb, count (contiguous)
  float* ds    = (float*)(count + NN);
  float* dirs  = ds + NE;
  float* posf  = dirs + 3*NE;
  float* embf  = posf + NN*3;
  float* b1f   = embf + 119*NF;               // 3*NF
  float* b2f_  = b1f + 3*NF;                  // 3*NF
  u32*   hb    = (u32*)(b2f_ + 3*NF);         // NN*64
  u16*   mesw  = (u16*)(hb + (size_t)NN*64);  // 3*4096
  u16*   w11sw = mesw  + 3*4096;
  u16*   w12sw = w11sw + 3*16384;
  u16*   w21sw = w12sw + 3*16384;
  u16*   w22sw = w21sw + 3*16384;
  u16*   w1sw  = w22sw + 3*16384;
  u16*   w2sw  = w1sw  + 3*16384;
  u16*   eusw  = w2sw  + 3*16384;
  int* rowptr  = (int*)(eusw + 3*16384);      // NN+1
  int* cursor  = rowptr + NN + 1;
  int* perm    = cursor + NN;                 // NE
  int* iis     = perm + NE;
  int* jjs     = iis + NE;

  k_detect<<<1, 256, 0, stream>>>(meW, 3*NB*NF, flag);

  // zero force + fdelta + forceb + count in one shot
  hipMemsetAsync(force, 0, ((size_t)NN*3*NF*2 + (size_t)NN*3*64 + NN)*4, stream);

  CvtArgs ca;
  ca.src[0]=pos;   ca.dst[0]=posf; ca.n[0]=NN*3;
  ca.src[1]=emb;   ca.dst[1]=embf; ca.n[1]=119*NF;
  ca.src[2]=mnpb1; ca.dst[2]=b1f;  ca.n[2]=3*NF;
  ca.src[3]=mnpb2; ca.dst[3]=b2f_; ca.n[3]=3*NF;
  k_cvt4<<<dim3(60,4), 256, 0, stream>>>(ca, flag);

  SwzArgs sa;
  sa.src[0]=em1W1; sa.dst[0]=w11sw;
  sa.src[1]=em1W2; sa.dst[1]=w12sw;
  sa.src[2]=em2W1; sa.dst[2]=w21sw;
  sa.src[3]=em2W2; sa.dst[3]=w22sw;
  sa.src[4]=mnpW1; sa.dst[4]=w1sw;
  sa.src[5]=mnpW2; sa.dst[5]=w2sw;
  sa.src[6]=euW;   sa.dst[6]=eusw;
  k_swz7 <<<dim3(192,7), 256, 0, stream>>>(sa, flag);
  k_swzme<<<(3*4096+255)/256, 256, 0, stream>>>(meW, mesw, flag);

  k_hist      <<<(NE+255)/256, 256, 0, stream>>>(ei, count);
  k_scan      <<<1, 256, 0, stream>>>(count, rowptr, cursor);
  k_scatter   <<<(NE+255)/256, 256, 0, stream>>>(ei, cursor, perm);
  k_edge_embed<<<(NE+255)/256, 256, 0, stream>>>(ei, perm, posf, iis, jjs, ds, dirs);
  k_init_atom <<<(NN*NF+255)/256, 256, 0, stream>>>(z, embf, atom);

  // layer 0 MLP standalone; thereafter fused with the preceding update
  k_node_mlp2<<<NN/16, 64, 0, stream>>>(atom,
      w1sw, b1f, w2sw, b2f_, hb);
  for (int l = 0; l < 3; l++){
    k_edge_mfma<<<NE/16, 64, 0, stream>>>(iis, jjs, ds, dirs, hb,
        mesw  + (size_t)l*4096,
        w11sw + (size_t)l*16384, w12sw + (size_t)l*16384,
        w21sw + (size_t)l*16384, w22sw + (size_t)l*16384,
        atom, forceb, fdelta);
    int nl = l + 1;
    k_node_fused<<<NN/16, 64, 0, stream>>>(force, fdelta,
        eusw + (size_t)l*16384, atom, forceb,
        w1sw + (size_t)(nl%3)*16384, b1f + (size_t)(nl%3)*NF,
        w2sw + (size_t)(nl%3)*16384, b2f_ + (size_t)(nl%3)*NF,
        hb, (l < 2) ? 1 : 0);
  }

  k_writeout<<<(NN*NF + NN*3*NF + 255)/256, 256, 0, stream>>>(atom, force, d_out, flag);
}

// Round 12
// 664.549 us; speedup vs baseline: 1.3925x; 1.0793x over previous
//
#include <hip/hip_runtime.h>
#include <hip/hip_bf16.h>
#include <math.h>

#define NN 10000
#define NE 160000
#define NF 128
#define NB 20
#define CUT 5.0f
#define TPS 136   // u16 tile row stride (even -> u32-pair flush reads aligned)

typedef __attribute__((ext_vector_type(8))) short short8;
typedef __attribute__((ext_vector_type(4))) float floatx4;
typedef unsigned short u16;
typedef unsigned int u32;

__device__ __forceinline__ u16 f2b(float x){
  union { __hip_bfloat16 b; u16 u; } cv;
  cv.b = __float2bfloat16(x);
  return cv.u;
}
__device__ __forceinline__ float b2f_raw(u16 x){ return __uint_as_float((u32)x << 16); }
__device__ __forceinline__ float lo_bf(u32 w){ return __uint_as_float(w << 16); }
__device__ __forceinline__ float hi_bf(u32 w){ return __uint_as_float(w & 0xFFFF0000u); }
__device__ __forceinline__ u32 packbf(float lo, float hi){
  return ((u32)f2b(hi) << 16) | (u32)f2b(lo);
}
__device__ __forceinline__ float fast_silu(float v){
  return v * __builtin_amdgcn_rcpf(1.f + __expf(-v));
}
__device__ __forceinline__ float rdf(const void* p, size_t i, int isb){
  return isb ? __bfloat162float(((const __hip_bfloat16*)p)[i]) : ((const float*)p)[i];
}

// ---------------- dtype detector: 1=bf16, 0=fp32 ----------------
__global__ __launch_bounds__(256) void k_detect(const void* __restrict__ w, int nelem,
                                                int* __restrict__ flag){
  __shared__ int cnt;
  if (threadIdx.x == 0) cnt = 0;
  __syncthreads();
  const u16* hw = (const u16*)w;
  int local = 0;
  for (int k = threadIdx.x; k < nelem; k += 256){
    u16 h = hw[k];
    int e = (h >> 7) & 0xFF;
    if ((h & 0x7FFF) == 0 || (e >= 103 && e <= 130)) local++;
  }
  atomicAdd(&cnt, local);
  __syncthreads();
  if (threadIdx.x == 0) *flag = (cnt >= (nelem * 9) / 10) ? 1 : 0;
}

// ---------------- single prep kernel: cvt x4 (y=0..3), swz128 x7 (y=4..10), swzme (y=11) ----------------
struct PrepArgs {
  const void* csrc[4]; float* cdst[4]; int cn[4];
  const void* ssrc[7]; u16* sdst[7];
  const void* mesrc;   u16* medst;
};
__global__ __launch_bounds__(256) void k_prep(PrepArgs a, const int* __restrict__ flag){
  int y = blockIdx.y;
  int isb = *flag;
  if (y < 4){
    const void* s = a.csrc[y]; float* d = a.cdst[y]; int n = a.cn[y];
    for (int i = blockIdx.x*256 + threadIdx.x; i < n; i += gridDim.x*256)
      d[i] = rdf(s, i, isb);
  } else if (y < 11){
    const void* s = a.ssrc[y-4]; u16* d = a.sdst[y-4];
    int idx = blockIdx.x*256 + threadIdx.x;        // 192*256 = 3*16384 exactly
    int l = idx >> 14, rem = idx & 16383;
    int j = rem & 7, lane = (rem >> 3) & 63, tn = (rem >> 9) & 7, tk = rem >> 12;
    int k = tk*32 + ((lane >> 4) & 3)*8 + j, n = tn*16 + (lane & 15);
    d[idx] = f2b(rdf(s, (size_t)l*16384 + k*NF + n, isb));
  } else {
    int idx = blockIdx.x*256 + threadIdx.x;
    if (idx >= 3*4096) return;
    int l = idx >> 12, rem = idx & 4095;
    int j = rem & 7, lane = (rem >> 3) & 63, tn = rem >> 9;
    int k = ((lane >> 4) & 3)*8 + j, n = tn*16 + (lane & 15);
    a.medst[idx] = (k < NB) ? f2b(rdf(a.mesrc, (size_t)l*NB*NF + k*NF + n, isb)) : (u16)0;
  }
}

// ---------------- counting sort: hist -> scan -> fused scatter+embed ----------------
__global__ __launch_bounds__(256) void k_hist(const int* __restrict__ ei, int* __restrict__ count){
  int e = blockIdx.x*256 + threadIdx.x;
  if (e < NE) atomicAdd(&count[ei[e]], 1);
}
__global__ __launch_bounds__(256) void k_scan(const int* __restrict__ count,
                                              int* __restrict__ rowptr, int* __restrict__ cursor){
  __shared__ int part[256];
  const int CH = (NN + 255) / 256;
  int t = threadIdx.x;
  int base = t * CH;
  int s = 0;
  for (int k = 0; k < CH; k++){ int i = base + k; if (i < NN) s += count[i]; }
  part[t] = s;
  __syncthreads();
  for (int off = 1; off < 256; off <<= 1){
    int v = (t >= off) ? part[t - off] : 0;
    __syncthreads();
    part[t] += v;
    __syncthreads();
  }
  int run = (t == 0) ? 0 : part[t - 1];
  for (int k = 0; k < CH; k++){
    int i = base + k;
    if (i < NN){ rowptr[i] = run; cursor[i] = run; run += count[i]; }
  }
  if (t == 255) rowptr[NN] = run;
}
// fused scatter + edge embedding: compute payload, write to sorted slot directly
__global__ __launch_bounds__(256) void k_scatter_embed(const int* __restrict__ ei,
                                                       int* __restrict__ cursor,
                                                       const float* __restrict__ pos,
                                                       int* __restrict__ iis, int* __restrict__ jjs,
                                                       float* __restrict__ ds, float* __restrict__ dirs){
  int e = blockIdx.x * 256 + threadIdx.x;
  if (e >= NE) return;
  int i = ei[e], j = ei[NE + e];
  float dx = pos[j*3+0] - pos[i*3+0];
  float dy = pos[j*3+1] - pos[i*3+1];
  float dz = pos[j*3+2] - pos[i*3+2];
  float d = sqrtf(dx*dx + dy*dy + dz*dz + 1e-12f);
  float inv = 1.0f / d;
  int s = atomicAdd(&cursor[i], 1);
  iis[s] = i; jjs[s] = j;
  ds[s] = d;
  dirs[s*3+0] = dx*inv; dirs[s*3+1] = dy*inv; dirs[s*3+2] = dz*inv;
}

// ---------------- layer-0 node MLP with fused atom init (emb[z] gather) ----------------
__global__ __launch_bounds__(64, 4) void k_mlp0(
    const int* __restrict__ z, const float* __restrict__ emb,
    float* __restrict__ atom,
    const u16* __restrict__ w1sw, const float* __restrict__ b1,
    const u16* __restrict__ w2sw, const float* __restrict__ b2,
    u32* __restrict__ hb)
{
  __shared__ __align__(16) u16 tileT[16][TPS];
  const int lane = threadIdx.x;
  const int q = lane >> 4, ln = lane & 15;
  const int n0 = blockIdx.x * 16;   // 625*16 = NN exactly
  const int zn = z[n0 + ln];        // row n0+ln's element type

  floatx4 c1[8];
  #pragma unroll
  for (int tn = 0; tn < 8; tn++) c1[tn] = (floatx4){0,0,0,0};
  #pragma unroll
  for (int tk = 0; tk < 4; tk++){
    const float4 u0 = *(const float4*)&emb[(size_t)zn*NF + tk*32 + q*8];
    const float4 u1 = *(const float4*)&emb[(size_t)zn*NF + tk*32 + q*8 + 4];
    // fused init: atom = emb[z]
    *(float4*)&atom[(size_t)(n0+ln)*NF + tk*32 + q*8]     = u0;
    *(float4*)&atom[(size_t)(n0+ln)*NF + tk*32 + q*8 + 4] = u1;
    short8 a;
    a[0]=(short)f2b(u0.x); a[1]=(short)f2b(u0.y); a[2]=(short)f2b(u0.z); a[3]=(short)f2b(u0.w);
    a[4]=(short)f2b(u1.x); a[5]=(short)f2b(u1.y); a[6]=(short)f2b(u1.z); a[7]=(short)f2b(u1.w);
    #pragma unroll
    for (int tn = 0; tn < 8; tn++){
      short8 b = *(const short8*)(w1sw + (size_t)((tk*8 + tn)*64 + lane)*8);
      c1[tn] = __builtin_amdgcn_mfma_f32_16x16x32_bf16(a, b, c1[tn], 0, 0, 0);
    }
  }
  #pragma unroll
  for (int tn = 0; tn < 8; tn++){
    int n = tn*16 + ln;
    float bias = b1[n];
    #pragma unroll
    for (int r = 0; r < 4; r++)
      tileT[q*4 + r][n] = f2b(fast_silu(c1[tn][r] + bias));
  }

  floatx4 c2[8];
  #pragma unroll
  for (int tn = 0; tn < 8; tn++) c2[tn] = (floatx4){0,0,0,0};
  #pragma unroll
  for (int tk = 0; tk < 4; tk++){
    short8 a = *(const short8*)&tileT[ln][tk*32 + q*8];
    #pragma unroll
    for (int tn = 0; tn < 8; tn++){
      short8 b = *(const short8*)(w2sw + (size_t)((tk*8 + tn)*64 + lane)*8);
      c2[tn] = __builtin_amdgcn_mfma_f32_16x16x32_bf16(a, b, c2[tn], 0, 0, 0);
    }
  }
  float b2n[8];
  #pragma unroll
  for (int tn = 0; tn < 8; tn++) b2n[tn] = b2[tn*16 + ln];
  #pragma unroll
  for (int tn = 0; tn < 4; tn++){
    #pragma unroll
    for (int r = 0; r < 4; r++){
      float vl = c2[tn][r]   + b2n[tn];
      float vh = c2[tn+4][r] + b2n[tn+4];
      hb[(size_t)(n0 + q*4 + r)*64 + tn*16 + ln] = packbf(vl, vh);
    }
  }
}

// ---------------- MFMA edge kernel: r6 body + u32-pair vectorized flushes ----------------
__global__ __launch_bounds__(64, 4) void k_edge_mfma(
    const int* __restrict__ iis, const int* __restrict__ jjs,
    const float* __restrict__ ds, const float* __restrict__ dirs,
    const u32* __restrict__ hb,
    const u16* __restrict__ mesw,
    const u16* __restrict__ w11sw, const u16* __restrict__ w12sw,
    const u16* __restrict__ w21sw, const u16* __restrict__ w22sw,
    float* __restrict__ atom, const u32* __restrict__ forceb, float* __restrict__ fdelta)
{
  __shared__ __align__(16) u16 tileM[16][TPS];
  __shared__ int iiS[16];

  const int lane = threadIdx.x;
  const int q = lane >> 4, ln = lane & 15;
  const int e0 = blockIdx.x * 16;   // grid = NE/16 exactly
  const int c0 = lane * 2;          // u32-pair flush columns

  if (lane < 16) iiS[lane] = iis[e0 + lane];

  int iiR[4], jjR[4];
  float dirR[4][3];
  #pragma unroll
  for (int r = 0; r < 4; r++){
    int s = e0 + q*4 + r;
    iiR[r] = iis[s]; jjR[r] = jjs[s];
    dirR[r][0] = dirs[s*3+0]; dirR[r][1] = dirs[s*3+1]; dirR[r][2] = dirs[s*3+2];
  }

  // paired h gathers
  u32 hiw[4][4], hjw[4][4];
  #pragma unroll
  for (int r = 0; r < 4; r++)
    #pragma unroll
    for (int t4 = 0; t4 < 4; t4++){
      hiw[r][t4] = hb[(size_t)iiR[r]*64 + t4*16 + ln];
      hjw[r][t4] = hb[(size_t)jjR[r]*64 + t4*16 + ln];
    }

  // rbf A-fragment (K padded 20->32)
  float dA  = ds[e0 + ln];
  float fcA = (dA < CUT) ? 0.5f*(cosf((float)M_PI*dA*(1.0f/CUT)) + 1.0f) : 0.0f;
  short8 a_rbf;
  #pragma unroll
  for (int j = 0; j < 8; j++){
    int k = q*8 + j;
    float v = 0.f;
    if (k < NB){
      float t = (dA - CUT*(float)k/(float)(NB-1)) * ((float)NB/CUT);
      v = __expf(-t*t) * fcA;
    }
    a_rbf[j] = (short)f2b(v);
  }

  // me = rbf @ meW; msg = me*h_i*h_j -> tileM (bf16)
  #pragma unroll
  for (int tn = 0; tn < 8; tn++){
    short8 b = *(const short8*)(mesw + (size_t)(tn*64 + lane)*8);
    floatx4 c = {0.f,0.f,0.f,0.f};
    c = __builtin_amdgcn_mfma_f32_16x16x32_bf16(a_rbf, b, c, 0, 0, 0);
    int n = tn*16 + ln;
    int t4 = tn & 3;
    #pragma unroll
    for (int r = 0; r < 4; r++){
      float hi_ = (tn < 4) ? lo_bf(hiw[r][t4]) : hi_bf(hiw[r][t4]);
      float hj_ = (tn < 4) ? lo_bf(hjw[r][t4]) : hi_bf(hjw[r][t4]);
      tileM[q*4 + r][n] = f2b(c[r] * hi_ * hj_);
    }
  }

  // atom segment flush (u32-pair LDS reads: lane owns cols c0, c0+1)
  {
    int seg = 0;
    for (int m = 1; m <= 16; m++){
      if (m == 16 || iiS[m] != iiS[seg]){
        int ii = iiS[seg];
        float s0 = 0.f, s1 = 0.f;
        for (int r = seg; r < m; r++){
          u32 w = *(const u32*)&tileM[r][c0];
          s0 += lo_bf(w); s1 += hi_bf(w);
        }
        atomicAdd(&atom[(size_t)ii*NF + c0],     s0);
        atomicAdd(&atom[(size_t)ii*NF + c0 + 1], s1);
        seg = m;
      }
    }
  }

  // c2 = msg @ w21 (held in regs as t2 after silu)
  floatx4 c2[8];
  #pragma unroll
  for (int tn = 0; tn < 8; tn++) c2[tn] = (floatx4){0,0,0,0};
  #pragma unroll
  for (int tk = 0; tk < 4; tk++){
    short8 a = *(const short8*)&tileM[ln][tk*32 + q*8];
    #pragma unroll
    for (int tn = 0; tn < 8; tn++){
      short8 b = *(const short8*)(w21sw + (size_t)((tk*8 + tn)*64 + lane)*8);
      c2[tn] = __builtin_amdgcn_mfma_f32_16x16x32_bf16(a, b, c2[tn], 0, 0, 0);
    }
  }
  // c1 = msg @ w11
  floatx4 c1[8];
  #pragma unroll
  for (int tn = 0; tn < 8; tn++) c1[tn] = (floatx4){0,0,0,0};
  #pragma unroll
  for (int tk = 0; tk < 4; tk++){
    short8 a = *(const short8*)&tileM[ln][tk*32 + q*8];
    #pragma unroll
    for (int tn = 0; tn < 8; tn++){
      short8 b = *(const short8*)(w11sw + (size_t)((tk*8 + tn)*64 + lane)*8);
      c1[tn] = __builtin_amdgcn_mfma_f32_16x16x32_bf16(a, b, c1[tn], 0, 0, 0);
    }
  }
  // t1 -> tileM ; t2 = silu(c2) stays in regs
  #pragma unroll
  for (int tn = 0; tn < 8; tn++){
    int n = tn*16 + ln;
    #pragma unroll
    for (int r = 0; r < 4; r++){
      tileM[q*4 + r][n] = f2b(fast_silu(c1[tn][r]));
      c2[tn][r] = fast_silu(c2[tn][r]);
    }
  }

  // g1 = t1 @ w12
  floatx4 g1[8];
  #pragma unroll
  for (int tn = 0; tn < 8; tn++) g1[tn] = (floatx4){0,0,0,0};
  #pragma unroll
  for (int tk = 0; tk < 4; tk++){
    short8 a = *(const short8*)&tileM[ln][tk*32 + q*8];
    #pragma unroll
    for (int tn = 0; tn < 8; tn++){
      short8 b = *(const short8*)(w12sw + (size_t)((tk*8 + tn)*64 + lane)*8);
      g1[tn] = __builtin_amdgcn_mfma_f32_16x16x32_bf16(a, b, g1[tn], 0, 0, 0);
    }
  }
  // t2 -> tileM
  #pragma unroll
  for (int tn = 0; tn < 8; tn++){
    int n = tn*16 + ln;
    #pragma unroll
    for (int r = 0; r < 4; r++) tileM[q*4 + r][n] = f2b(c2[tn][r]);
  }
  // g2 = t2 @ w22 (reuse c1)
  #pragma unroll
  for (int tn = 0; tn < 8; tn++) c1[tn] = (floatx4){0,0,0,0};
  #pragma unroll
  for (int tk = 0; tk < 4; tk++){
    short8 a = *(const short8*)&tileM[ln][tk*32 + q*8];
    #pragma unroll
    for (int tn = 0; tn < 8; tn++){
      short8 b = *(const short8*)(w22sw + (size_t)((tk*8 + tn)*64 + lane)*8);
      c1[tn] = __builtin_amdgcn_mfma_f32_16x16x32_bf16(a, b, c1[tn], 0, 0, 0);
    }
  }

  // three d-passes: tileM <- g1*dir + g2*force_old[j]; u32-pair segment flush -> fdelta
  for (int d = 0; d < 3; d++){
    u32 fjw[4][4];
    #pragma unroll
    for (int r = 0; r < 4; r++)
      #pragma unroll
      for (int t4 = 0; t4 < 4; t4++)
        fjw[r][t4] = forceb[((size_t)jjR[r]*3 + d)*64 + t4*16 + ln];
    #pragma unroll
    for (int tn = 0; tn < 8; tn++){
      int n = tn*16 + ln;
      int t4 = tn & 3;
      #pragma unroll
      for (int r = 0; r < 4; r++){
        float fj = (tn < 4) ? lo_bf(fjw[r][t4]) : hi_bf(fjw[r][t4]);
        tileM[q*4 + r][n] = f2b(g1[tn][r]*dirR[r][d] + c1[tn][r]*fj);
      }
    }
    int seg = 0;
    for (int m = 1; m <= 16; m++){
      if (m == 16 || iiS[m] != iiS[seg]){
        int ii = iiS[seg];
        float s0 = 0.f, s1 = 0.f;
        for (int r = seg; r < m; r++){
          u32 w = *(const u32*)&tileM[r][c0];
          s0 += lo_bf(w); s1 += hi_bf(w);
        }
        atomicAdd(&fdelta[((size_t)ii*3 + d)*NF + c0],     s0);
        atomicAdd(&fdelta[((size_t)ii*3 + d)*NF + c0 + 1], s1);
        seg = m;
      }
    }
  }
}

// ---------------- fused node kernel: update(l) + MLP(l+1) ----------------
__global__ __launch_bounds__(64, 2) void k_node_fused(
    float* __restrict__ force, float* __restrict__ fdelta,
    const u16* __restrict__ eusw, float* __restrict__ atom,
    u32* __restrict__ forceb,
    const u16* __restrict__ w1sw, const float* __restrict__ b1,
    const u16* __restrict__ w2sw, const float* __restrict__ b2,
    u32* __restrict__ hb, int do_mlp)
{
  __shared__ __align__(16) u16 tile[16][TPS];
  const int lane = threadIdx.x;
  const int q = lane >> 4, ln = lane & 15;
  const int n0 = blockIdx.x * 16;   // 625*16 = NN exactly

  floatx4 sacc[8];
  #pragma unroll
  for (int tn = 0; tn < 8; tn++) sacc[tn] = (floatx4){0,0,0,0};

  for (int d = 0; d < 3; d++){
    #pragma unroll
    for (int m = 0; m < 16; m++){
      size_t idx = ((size_t)(n0+m)*3 + d)*NF + lane;
      float v0 = force[idx]    + fdelta[idx];
      float v1 = force[idx+64] + fdelta[idx+64];
      force[idx] = v0; force[idx+64] = v1;
      fdelta[idx] = 0.f; fdelta[idx+64] = 0.f;
      forceb[((size_t)(n0+m)*3 + d)*64 + lane] = packbf(v0, v1);
      tile[m][lane]    = f2b(v0);
      tile[m][lane+64] = f2b(v1);
    }
    floatx4 c[8];
    #pragma unroll
    for (int tn = 0; tn < 8; tn++) c[tn] = (floatx4){0,0,0,0};
    #pragma unroll
    for (int tk = 0; tk < 4; tk++){
      short8 a = *(const short8*)&tile[ln][tk*32 + q*8];
      #pragma unroll
      for (int tn = 0; tn < 8; tn++){
        short8 b = *(const short8*)(eusw + (size_t)((tk*8 + tn)*64 + lane)*8);
        c[tn] = __builtin_amdgcn_mfma_f32_16x16x32_bf16(a, b, c[tn], 0, 0, 0);
      }
    }
    #pragma unroll
    for (int tn = 0; tn < 8; tn++){
      int n = tn*16 + ln;
      #pragma unroll
      for (int r = 0; r < 4; r++)
        sacc[tn][r] += b2f_raw(tile[q*4 + r][n]) * c[tn][r];
    }
  }
  float anew[8][4];
  #pragma unroll
  for (int tn = 0; tn < 8; tn++){
    int n = tn*16 + ln;
    #pragma unroll
    for (int r = 0; r < 4; r++){
      size_t idx = (size_t)(n0 + q*4 + r)*NF + n;
      float v = atom[idx] + sacc[tn][r];
      atom[idx] = v;
      anew[tn][r] = v;
    }
  }
  if (!do_mlp) return;

  // ---- phase 2: h(l+1) ----
  #pragma unroll
  for (int tn = 0; tn < 8; tn++){
    int n = tn*16 + ln;
    #pragma unroll
    for (int r = 0; r < 4; r++) tile[q*4 + r][n] = f2b(anew[tn][r]);
  }
  floatx4 c1[8];
  #pragma unroll
  for (int tn = 0; tn < 8; tn++) c1[tn] = (floatx4){0,0,0,0};
  #pragma unroll
  for (int tk = 0; tk < 4; tk++){
    short8 a = *(const short8*)&tile[ln][tk*32 + q*8];
    #pragma unroll
    for (int tn = 0; tn < 8; tn++){
      short8 b = *(const short8*)(w1sw + (size_t)((tk*8 + tn)*64 + lane)*8);
      c1[tn] = __builtin_amdgcn_mfma_f32_16x16x32_bf16(a, b, c1[tn], 0, 0, 0);
    }
  }
  #pragma unroll
  for (int tn = 0; tn < 8; tn++){
    int n = tn*16 + ln;
    float bias = b1[n];
    #pragma unroll
    for (int r = 0; r < 4; r++)
      tile[q*4 + r][n] = f2b(fast_silu(c1[tn][r] + bias));
  }
  floatx4 c2[8];
  #pragma unroll
  for (int tn = 0; tn < 8; tn++) c2[tn] = (floatx4){0,0,0,0};
  #pragma unroll
  for (int tk = 0; tk < 4; tk++){
    short8 a = *(const short8*)&tile[ln][tk*32 + q*8];
    #pragma unroll
    for (int tn = 0; tn < 8; tn++){
      short8 b = *(const short8*)(w2sw + (size_t)((tk*8 + tn)*64 + lane)*8);
      c2[tn] = __builtin_amdgcn_mfma_f32_16x16x32_bf16(a, b, c2[tn], 0, 0, 0);
    }
  }
  float b2n[8];
  #pragma unroll
  for (int tn = 0; tn < 8; tn++) b2n[tn] = b2[tn*16 + ln];
  #pragma unroll
  for (int tn = 0; tn < 4; tn++){
    #pragma unroll
    for (int r = 0; r < 4; r++){
      float vl = c2[tn][r]   + b2n[tn];
      float vh = c2[tn+4][r] + b2n[tn+4];
      hb[(size_t)(n0 + q*4 + r)*64 + tn*16 + ln] = packbf(vl, vh);
    }
  }
}

// ---------------- write out ----------------
__global__ __launch_bounds__(256) void k_writeout(const float* __restrict__ atom,
                                                  const float* __restrict__ force,
                                                  void* __restrict__ out,
                                                  const int* __restrict__ flag){
  int idx = blockIdx.x * 256 + threadIdx.x;
  const int na = NN * NF;
  const int tot = na + NN * 3 * NF;
  if (idx >= tot) return;
  float v = (idx < na) ? atom[idx] : force[idx - na];
  if (*flag) ((__hip_bfloat16*)out)[idx] = __float2bfloat16(v);
  else       ((float*)out)[idx] = v;
}

extern "C" void kernel_launch(void* const* d_in, const int* in_sizes, int n_in,
                              void* d_out, int out_size, void* d_ws, size_t ws_size,
                              hipStream_t stream){
  const int* z    = (const int*)d_in[0];
  const void* pos = d_in[1];
  // d_in[2] cell, d_in[3] batch: numerically dead (sym == I)
  const int* ei   = (const int*)d_in[4];
  const void* emb   = d_in[5];
  const void* mnpW1 = d_in[6];
  const void* mnpb1 = d_in[7];
  const void* mnpW2 = d_in[8];
  const void* mnpb2 = d_in[9];
  const void* meW   = d_in[10];
  const void* em1W1 = d_in[11];
  const void* em1W2 = d_in[12];
  const void* em2W1 = d_in[13];
  const void* em2W2 = d_in[14];
  const void* euW   = d_in[15];

  float* base  = (float*)d_ws;
  int*   flag  = (int*)d_ws;                  // 4 floats reserved
  float* atom   = base + 4;                   // NN*NF
  float* force  = atom   + NN*NF;             // NN*3*NF
  float* fdelta = force  + (size_t)NN*3*NF;   // NN*3*NF
  u32*   forceb = (u32*)(fdelta + (size_t)NN*3*NF);  // NN*3*64
  int*   count  = (int*)(forceb + (size_t)NN*3*64);  // NN
  // single memset zeroes force, fdelta, forceb, count (contiguous)
  float* ds    = (float*)(count + NN);
  float* dirs  = ds + NE;
  float* posf  = dirs + 3*NE;
  float* embf  = posf + NN*3;
  float* b1f   = embf + 119*NF;               // 3*NF
  float* b2f_  = b1f + 3*NF;                  // 3*NF
  u32*   hb    = (u32*)(b2f_ + 3*NF);         // NN*64
  u16*   mesw  = (u16*)(hb + (size_t)NN*64);  // 3*4096
  u16*   w11sw = mesw  + 3*4096;
  u16*   w12sw = w11sw + 3*16384;
  u16*   w21sw = w12sw + 3*16384;
  u16*   w22sw = w21sw + 3*16384;
  u16*   w1sw  = w22sw + 3*16384;
  u16*   w2sw  = w1sw  + 3*16384;
  u16*   eusw  = w2sw  + 3*16384;
  int* rowptr  = (int*)(eusw + 3*16384);      // NN+1
  int* cursor  = rowptr + NN + 1;
  int* iis     = cursor + NN;                 // NE
  int* jjs     = iis + NE;

  k_detect<<<1, 256, 0, stream>>>(meW, 3*NB*NF, flag);

  // zero force + fdelta + forceb + count in one shot
  hipMemsetAsync(force, 0, ((size_t)NN*3*NF*2 + (size_t)NN*3*64 + NN)*4, stream);

  PrepArgs pa;
  pa.csrc[0]=pos;   pa.cdst[0]=posf; pa.cn[0]=NN*3;
  pa.csrc[1]=emb;   pa.cdst[1]=embf; pa.cn[1]=119*NF;
  pa.csrc[2]=mnpb1; pa.cdst[2]=b1f;  pa.cn[2]=3*NF;
  pa.csrc[3]=mnpb2; pa.cdst[3]=b2f_; pa.cn[3]=3*NF;
  pa.ssrc[0]=em1W1; pa.sdst[0]=w11sw;
  pa.ssrc[1]=em1W2; pa.sdst[1]=w12sw;
  pa.ssrc[2]=em2W1; pa.sdst[2]=w21sw;
  pa.ssrc[3]=em2W2; pa.sdst[3]=w22sw;
  pa.ssrc[4]=mnpW1; pa.sdst[4]=w1sw;
  pa.ssrc[5]=mnpW2; pa.sdst[5]=w2sw;
  pa.ssrc[6]=euW;   pa.sdst[6]=eusw;
  pa.mesrc=meW;     pa.medst=mesw;
  k_prep<<<dim3(192,12), 256, 0, stream>>>(pa, flag);

  k_hist         <<<(NE+255)/256, 256, 0, stream>>>(ei, count);
  k_scan         <<<1, 256, 0, stream>>>(count, rowptr, cursor);
  k_scatter_embed<<<(NE+255)/256, 256, 0, stream>>>(ei, cursor, posf, iis, jjs, ds, dirs);

  // layer 0 MLP with fused atom init
  k_mlp0<<<NN/16, 64, 0, stream>>>(z, embf, atom, w1sw, b1f, w2sw, b2f_, hb);
  for (int l = 0; l < 3; l++){
    k_edge_mfma<<<NE/16, 64, 0, stream>>>(iis, jjs, ds, dirs, hb,
        mesw  + (size_t)l*4096,
        w11sw + (size_t)l*16384, w12sw + (size_t)l*16384,
        w21sw + (size_t)l*16384, w22sw + (size_t)l*16384,
        atom, forceb, fdelta);
    int nl = l + 1;
    k_node_fused<<<NN/16, 64, 0, stream>>>(force, fdelta,
        eusw + (size_t)l*16384, atom, forceb,
        w1sw + (size_t)(nl%3)*16384, b1f + (size_t)(nl%3)*NF,
        w2sw + (size_t)(nl%3)*16384, b2f_ + (size_t)(nl%3)*NF,
        hb, (l < 2) ? 1 : 0);
  }

  k_writeout<<<(NN*NF + NN*3*NF + 255)/256, 256, 0, stream>>>(atom, force, d_out, flag);
}

// Round 13
// 616.857 us; speedup vs baseline: 1.5001x; 1.0773x over previous
//
#include <hip/hip_runtime.h>
#include <hip/hip_bf16.h>
#include <math.h>

#define NN 10000
#define NE 160000
#define NF 128
#define NB 20
#define CUT 5.0f
#define TPS 136   // u16 tile row stride
#define TPF 132   // fp32 tile row stride (even -> float2 aligned)

typedef __attribute__((ext_vector_type(8))) short short8;
typedef __attribute__((ext_vector_type(4))) float floatx4;
typedef unsigned short u16;
typedef unsigned int u32;

__device__ __forceinline__ u16 f2b(float x){
  union { __hip_bfloat16 b; u16 u; } cv;
  cv.b = __float2bfloat16(x);
  return cv.u;
}
__device__ __forceinline__ float b2f_raw(u16 x){ return __uint_as_float((u32)x << 16); }
__device__ __forceinline__ float lo_bf(u32 w){ return __uint_as_float(w << 16); }
__device__ __forceinline__ float hi_bf(u32 w){ return __uint_as_float(w & 0xFFFF0000u); }
__device__ __forceinline__ u32 packbf(float lo, float hi){
  return ((u32)f2b(hi) << 16) | (u32)f2b(lo);
}
__device__ __forceinline__ float fast_silu(float v){
  return v * __builtin_amdgcn_rcpf(1.f + __expf(-v));
}
__device__ __forceinline__ float rdf(const void* p, size_t i, int isb){
  return isb ? __bfloat162float(((const __hip_bfloat16*)p)[i]) : ((const float*)p)[i];
}

// ---------------- dtype detector: 1=bf16, 0=fp32 ----------------
__global__ __launch_bounds__(256) void k_detect(const void* __restrict__ w, int nelem,
                                                int* __restrict__ flag){
  __shared__ int cnt;
  if (threadIdx.x == 0) cnt = 0;
  __syncthreads();
  const u16* hw = (const u16*)w;
  int local = 0;
  for (int k = threadIdx.x; k < nelem; k += 256){
    u16 h = hw[k];
    int e = (h >> 7) & 0xFF;
    if ((h & 0x7FFF) == 0 || (e >= 103 && e <= 130)) local++;
  }
  atomicAdd(&cnt, local);
  __syncthreads();
  if (threadIdx.x == 0) *flag = (cnt >= (nelem * 9) / 10) ? 1 : 0;
}

// ---------------- single prep kernel: cvt x4 (y=0..3), swz128 x7 (y=4..10), swzme (y=11) ----------------
struct PrepArgs {
  const void* csrc[4]; float* cdst[4]; int cn[4];
  const void* ssrc[7]; u16* sdst[7];
  const void* mesrc;   u16* medst;
};
__global__ __launch_bounds__(256) void k_prep(PrepArgs a, const int* __restrict__ flag){
  int y = blockIdx.y;
  int isb = *flag;
  if (y < 4){
    const void* s = a.csrc[y]; float* d = a.cdst[y]; int n = a.cn[y];
    for (int i = blockIdx.x*256 + threadIdx.x; i < n; i += gridDim.x*256)
      d[i] = rdf(s, i, isb);
  } else if (y < 11){
    const void* s = a.ssrc[y-4]; u16* d = a.sdst[y-4];
    int idx = blockIdx.x*256 + threadIdx.x;        // 192*256 = 3*16384 exactly
    int l = idx >> 14, rem = idx & 16383;
    int j = rem & 7, lane = (rem >> 3) & 63, tn = (rem >> 9) & 7, tk = rem >> 12;
    int k = tk*32 + ((lane >> 4) & 3)*8 + j, n = tn*16 + (lane & 15);
    d[idx] = f2b(rdf(s, (size_t)l*16384 + k*NF + n, isb));
  } else {
    int idx = blockIdx.x*256 + threadIdx.x;
    if (idx >= 3*4096) return;
    int l = idx >> 12, rem = idx & 4095;
    int j = rem & 7, lane = (rem >> 3) & 63, tn = rem >> 9;
    int k = ((lane >> 4) & 3)*8 + j, n = tn*16 + (lane & 15);
    a.medst[idx] = (k < NB) ? f2b(rdf(a.mesrc, (size_t)l*NB*NF + k*NF + n, isb)) : (u16)0;
  }
}

// ---------------- counting sort: hist -> scan -> fused scatter+embed ----------------
__global__ __launch_bounds__(256) void k_hist(const int* __restrict__ ei, int* __restrict__ count){
  int e = blockIdx.x*256 + threadIdx.x;
  if (e < NE) atomicAdd(&count[ei[e]], 1);
}
__global__ __launch_bounds__(256) void k_scan(const int* __restrict__ count,
                                              int* __restrict__ rowptr, int* __restrict__ cursor){
  __shared__ int part[256];
  const int CH = (NN + 255) / 256;
  int t = threadIdx.x;
  int base = t * CH;
  int s = 0;
  for (int k = 0; k < CH; k++){ int i = base + k; if (i < NN) s += count[i]; }
  part[t] = s;
  __syncthreads();
  for (int off = 1; off < 256; off <<= 1){
    int v = (t >= off) ? part[t - off] : 0;
    __syncthreads();
    part[t] += v;
    __syncthreads();
  }
  int run = (t == 0) ? 0 : part[t - 1];
  for (int k = 0; k < CH; k++){
    int i = base + k;
    if (i < NN){ rowptr[i] = run; cursor[i] = run; run += count[i]; }
  }
  if (t == 255) rowptr[NN] = run;
}
__global__ __launch_bounds__(256) void k_scatter_embed(const int* __restrict__ ei,
                                                       int* __restrict__ cursor,
                                                       const float* __restrict__ pos,
                                                       int* __restrict__ iis, int* __restrict__ jjs,
                                                       float* __restrict__ ds, float* __restrict__ dirs){
  int e = blockIdx.x * 256 + threadIdx.x;
  if (e >= NE) return;
  int i = ei[e], j = ei[NE + e];
  float dx = pos[j*3+0] - pos[i*3+0];
  float dy = pos[j*3+1] - pos[i*3+1];
  float dz = pos[j*3+2] - pos[i*3+2];
  float d = sqrtf(dx*dx + dy*dy + dz*dz + 1e-12f);
  float inv = 1.0f / d;
  int s = atomicAdd(&cursor[i], 1);
  iis[s] = i; jjs[s] = j;
  ds[s] = d;
  dirs[s*3+0] = dx*inv; dirs[s*3+1] = dy*inv; dirs[s*3+2] = dz*inv;
}

// ---------------- layer-0 node MLP with fused atom init (emb[z] gather) ----------------
__global__ __launch_bounds__(64, 4) void k_mlp0(
    const int* __restrict__ z, const float* __restrict__ emb,
    float* __restrict__ atom,
    const u16* __restrict__ w1sw, const float* __restrict__ b1,
    const u16* __restrict__ w2sw, const float* __restrict__ b2,
    u32* __restrict__ hb)
{
  __shared__ __align__(16) u16 tileT[16][TPS];
  const int lane = threadIdx.x;
  const int q = lane >> 4, ln = lane & 15;
  const int n0 = blockIdx.x * 16;   // 625*16 = NN exactly
  const int zn = z[n0 + ln];

  floatx4 c1[8];
  #pragma unroll
  for (int tn = 0; tn < 8; tn++) c1[tn] = (floatx4){0,0,0,0};
  #pragma unroll
  for (int tk = 0; tk < 4; tk++){
    const float4 u0 = *(const float4*)&emb[(size_t)zn*NF + tk*32 + q*8];
    const float4 u1 = *(const float4*)&emb[(size_t)zn*NF + tk*32 + q*8 + 4];
    *(float4*)&atom[(size_t)(n0+ln)*NF + tk*32 + q*8]     = u0;
    *(float4*)&atom[(size_t)(n0+ln)*NF + tk*32 + q*8 + 4] = u1;
    short8 a;
    a[0]=(short)f2b(u0.x); a[1]=(short)f2b(u0.y); a[2]=(short)f2b(u0.z); a[3]=(short)f2b(u0.w);
    a[4]=(short)f2b(u1.x); a[5]=(short)f2b(u1.y); a[6]=(short)f2b(u1.z); a[7]=(short)f2b(u1.w);
    #pragma unroll
    for (int tn = 0; tn < 8; tn++){
      short8 b = *(const short8*)(w1sw + (size_t)((tk*8 + tn)*64 + lane)*8);
      c1[tn] = __builtin_amdgcn_mfma_f32_16x16x32_bf16(a, b, c1[tn], 0, 0, 0);
    }
  }
  #pragma unroll
  for (int tn = 0; tn < 8; tn++){
    int n = tn*16 + ln;
    float bias = b1[n];
    #pragma unroll
    for (int r = 0; r < 4; r++)
      tileT[q*4 + r][n] = f2b(fast_silu(c1[tn][r] + bias));
  }

  floatx4 c2[8];
  #pragma unroll
  for (int tn = 0; tn < 8; tn++) c2[tn] = (floatx4){0,0,0,0};
  #pragma unroll
  for (int tk = 0; tk < 4; tk++){
    short8 a = *(const short8*)&tileT[ln][tk*32 + q*8];
    #pragma unroll
    for (int tn = 0; tn < 8; tn++){
      short8 b = *(const short8*)(w2sw + (size_t)((tk*8 + tn)*64 + lane)*8);
      c2[tn] = __builtin_amdgcn_mfma_f32_16x16x32_bf16(a, b, c2[tn], 0, 0, 0);
    }
  }
  float b2n[8];
  #pragma unroll
  for (int tn = 0; tn < 8; tn++) b2n[tn] = b2[tn*16 + ln];
  #pragma unroll
  for (int tn = 0; tn < 4; tn++){
    #pragma unroll
    for (int r = 0; r < 4; r++){
      float vl = c2[tn][r]   + b2n[tn];
      float vh = c2[tn+4][r] + b2n[tn+4];
      hb[(size_t)(n0 + q*4 + r)*64 + tn*16 + ln] = packbf(vl, vh);
    }
  }
}

// ---------------- MFMA edge kernel: fp32 flush tile (accuracy), bf16 MFMA tile ----------------
__global__ __launch_bounds__(64, 4) void k_edge_mfma(
    const int* __restrict__ iis, const int* __restrict__ jjs,
    const float* __restrict__ ds, const float* __restrict__ dirs,
    const u32* __restrict__ hb,
    const u16* __restrict__ mesw,
    const u16* __restrict__ w11sw, const u16* __restrict__ w12sw,
    const u16* __restrict__ w21sw, const u16* __restrict__ w22sw,
    float* __restrict__ atom, const u32* __restrict__ forceb, float* __restrict__ fdelta)
{
  __shared__ __align__(16) u16 tileM[16][TPS];
  __shared__ __align__(16) float tileF[16][TPF];   // fp32 flush staging (never an MFMA input)
  __shared__ int iiS[16];

  const int lane = threadIdx.x;
  const int q = lane >> 4, ln = lane & 15;
  const int e0 = blockIdx.x * 16;   // grid = NE/16 exactly
  const int c0 = lane * 2;          // float2 flush columns

  if (lane < 16) iiS[lane] = iis[e0 + lane];

  int iiR[4], jjR[4];
  float dirR[4][3];
  #pragma unroll
  for (int r = 0; r < 4; r++){
    int s = e0 + q*4 + r;
    iiR[r] = iis[s]; jjR[r] = jjs[s];
    dirR[r][0] = dirs[s*3+0]; dirR[r][1] = dirs[s*3+1]; dirR[r][2] = dirs[s*3+2];
  }

  // paired h gathers
  u32 hiw[4][4], hjw[4][4];
  #pragma unroll
  for (int r = 0; r < 4; r++)
    #pragma unroll
    for (int t4 = 0; t4 < 4; t4++){
      hiw[r][t4] = hb[(size_t)iiR[r]*64 + t4*16 + ln];
      hjw[r][t4] = hb[(size_t)jjR[r]*64 + t4*16 + ln];
    }

  // rbf A-fragment (K padded 20->32)
  float dA  = ds[e0 + ln];
  float fcA = (dA < CUT) ? 0.5f*(cosf((float)M_PI*dA*(1.0f/CUT)) + 1.0f) : 0.0f;
  short8 a_rbf;
  #pragma unroll
  for (int j = 0; j < 8; j++){
    int k = q*8 + j;
    float v = 0.f;
    if (k < NB){
      float t = (dA - CUT*(float)k/(float)(NB-1)) * ((float)NB/CUT);
      v = __expf(-t*t) * fcA;
    }
    a_rbf[j] = (short)f2b(v);
  }

  // me = rbf @ meW; msg = me*h_i*h_j -> tileF (fp32, for flush) + tileM (bf16, for MFMA)
  #pragma unroll
  for (int tn = 0; tn < 8; tn++){
    short8 b = *(const short8*)(mesw + (size_t)(tn*64 + lane)*8);
    floatx4 c = {0.f,0.f,0.f,0.f};
    c = __builtin_amdgcn_mfma_f32_16x16x32_bf16(a_rbf, b, c, 0, 0, 0);
    int n = tn*16 + ln;
    int t4 = tn & 3;
    #pragma unroll
    for (int r = 0; r < 4; r++){
      float hi_ = (tn < 4) ? lo_bf(hiw[r][t4]) : hi_bf(hiw[r][t4]);
      float hj_ = (tn < 4) ? lo_bf(hjw[r][t4]) : hi_bf(hjw[r][t4]);
      float mv = c[r] * hi_ * hj_;
      tileF[q*4 + r][n] = mv;
      tileM[q*4 + r][n] = f2b(mv);
    }
  }

  // atom segment flush from fp32 tile (float2 per lane)
  {
    int seg = 0;
    for (int m = 1; m <= 16; m++){
      if (m == 16 || iiS[m] != iiS[seg]){
        int ii = iiS[seg];
        float s0 = 0.f, s1 = 0.f;
        for (int r = seg; r < m; r++){
          float2 w = *(const float2*)&tileF[r][c0];
          s0 += w.x; s1 += w.y;
        }
        atomicAdd(&atom[(size_t)ii*NF + c0],     s0);
        atomicAdd(&atom[(size_t)ii*NF + c0 + 1], s1);
        seg = m;
      }
    }
  }

  // c2 = msg @ w21 (held in regs as t2 after silu)
  floatx4 c2[8];
  #pragma unroll
  for (int tn = 0; tn < 8; tn++) c2[tn] = (floatx4){0,0,0,0};
  #pragma unroll
  for (int tk = 0; tk < 4; tk++){
    short8 a = *(const short8*)&tileM[ln][tk*32 + q*8];
    #pragma unroll
    for (int tn = 0; tn < 8; tn++){
      short8 b = *(const short8*)(w21sw + (size_t)((tk*8 + tn)*64 + lane)*8);
      c2[tn] = __builtin_amdgcn_mfma_f32_16x16x32_bf16(a, b, c2[tn], 0, 0, 0);
    }
  }
  // c1 = msg @ w11
  floatx4 c1[8];
  #pragma unroll
  for (int tn = 0; tn < 8; tn++) c1[tn] = (floatx4){0,0,0,0};
  #pragma unroll
  for (int tk = 0; tk < 4; tk++){
    short8 a = *(const short8*)&tileM[ln][tk*32 + q*8];
    #pragma unroll
    for (int tn = 0; tn < 8; tn++){
      short8 b = *(const short8*)(w11sw + (size_t)((tk*8 + tn)*64 + lane)*8);
      c1[tn] = __builtin_amdgcn_mfma_f32_16x16x32_bf16(a, b, c1[tn], 0, 0, 0);
    }
  }
  // t1 -> tileM ; t2 = silu(c2) stays in regs
  #pragma unroll
  for (int tn = 0; tn < 8; tn++){
    int n = tn*16 + ln;
    #pragma unroll
    for (int r = 0; r < 4; r++){
      tileM[q*4 + r][n] = f2b(fast_silu(c1[tn][r]));
      c2[tn][r] = fast_silu(c2[tn][r]);
    }
  }

  // g1 = t1 @ w12
  floatx4 g1[8];
  #pragma unroll
  for (int tn = 0; tn < 8; tn++) g1[tn] = (floatx4){0,0,0,0};
  #pragma unroll
  for (int tk = 0; tk < 4; tk++){
    short8 a = *(const short8*)&tileM[ln][tk*32 + q*8];
    #pragma unroll
    for (int tn = 0; tn < 8; tn++){
      short8 b = *(const short8*)(w12sw + (size_t)((tk*8 + tn)*64 + lane)*8);
      g1[tn] = __builtin_amdgcn_mfma_f32_16x16x32_bf16(a, b, g1[tn], 0, 0, 0);
    }
  }
  // t2 -> tileM
  #pragma unroll
  for (int tn = 0; tn < 8; tn++){
    int n = tn*16 + ln;
    #pragma unroll
    for (int r = 0; r < 4; r++) tileM[q*4 + r][n] = f2b(c2[tn][r]);
  }
  // g2 = t2 @ w22 (reuse c1)
  #pragma unroll
  for (int tn = 0; tn < 8; tn++) c1[tn] = (floatx4){0,0,0,0};
  #pragma unroll
  for (int tk = 0; tk < 4; tk++){
    short8 a = *(const short8*)&tileM[ln][tk*32 + q*8];
    #pragma unroll
    for (int tn = 0; tn < 8; tn++){
      short8 b = *(const short8*)(w22sw + (size_t)((tk*8 + tn)*64 + lane)*8);
      c1[tn] = __builtin_amdgcn_mfma_f32_16x16x32_bf16(a, b, c1[tn], 0, 0, 0);
    }
  }

  // three d-passes: tileF <- g1*dir + g2*force_old[j] (fp32, no rounding); flush -> fdelta
  for (int d = 0; d < 3; d++){
    u32 fjw[4][4];
    #pragma unroll
    for (int r = 0; r < 4; r++)
      #pragma unroll
      for (int t4 = 0; t4 < 4; t4++)
        fjw[r][t4] = forceb[((size_t)jjR[r]*3 + d)*64 + t4*16 + ln];
    #pragma unroll
    for (int tn = 0; tn < 8; tn++){
      int n = tn*16 + ln;
      int t4 = tn & 3;
      #pragma unroll
      for (int r = 0; r < 4; r++){
        float fj = (tn < 4) ? lo_bf(fjw[r][t4]) : hi_bf(fjw[r][t4]);
        tileF[q*4 + r][n] = g1[tn][r]*dirR[r][d] + c1[tn][r]*fj;
      }
    }
    int seg = 0;
    for (int m = 1; m <= 16; m++){
      if (m == 16 || iiS[m] != iiS[seg]){
        int ii = iiS[seg];
        float s0 = 0.f, s1 = 0.f;
        for (int r = seg; r < m; r++){
          float2 w = *(const float2*)&tileF[r][c0];
          s0 += w.x; s1 += w.y;
        }
        atomicAdd(&fdelta[((size_t)ii*3 + d)*NF + c0],     s0);
        atomicAdd(&fdelta[((size_t)ii*3 + d)*NF + c0 + 1], s1);
        seg = m;
      }
    }
  }
}

// ---------------- fused node kernel: update(l) + MLP(l+1), fp32 elementwise factor ----------------
__global__ __launch_bounds__(64, 2) void k_node_fused(
    float* __restrict__ force, float* __restrict__ fdelta,
    const u16* __restrict__ eusw, float* __restrict__ atom,
    u32* __restrict__ forceb,
    const u16* __restrict__ w1sw, const float* __restrict__ b1,
    const u16* __restrict__ w2sw, const float* __restrict__ b2,
    u32* __restrict__ hb, int do_mlp)
{
  __shared__ __align__(16) u16 tile[16][TPS];
  __shared__ __align__(16) float tileF[16][TPF];
  const int lane = threadIdx.x;
  const int q = lane >> 4, ln = lane & 15;
  const int n0 = blockIdx.x * 16;   // 625*16 = NN exactly

  floatx4 sacc[8];
  #pragma unroll
  for (int tn = 0; tn < 8; tn++) sacc[tn] = (floatx4){0,0,0,0};

  for (int d = 0; d < 3; d++){
    #pragma unroll
    for (int m = 0; m < 16; m++){
      size_t idx = ((size_t)(n0+m)*3 + d)*NF + lane;
      float v0 = force[idx]    + fdelta[idx];
      float v1 = force[idx+64] + fdelta[idx+64];
      force[idx] = v0; force[idx+64] = v1;
      fdelta[idx] = 0.f; fdelta[idx+64] = 0.f;
      forceb[((size_t)(n0+m)*3 + d)*64 + lane] = packbf(v0, v1);
      tile[m][lane]    = f2b(v0);
      tile[m][lane+64] = f2b(v1);
      tileF[m][lane]    = v0;
      tileF[m][lane+64] = v1;
    }
    floatx4 c[8];
    #pragma unroll
    for (int tn = 0; tn < 8; tn++) c[tn] = (floatx4){0,0,0,0};
    #pragma unroll
    for (int tk = 0; tk < 4; tk++){
      short8 a = *(const short8*)&tile[ln][tk*32 + q*8];
      #pragma unroll
      for (int tn = 0; tn < 8; tn++){
        short8 b = *(const short8*)(eusw + (size_t)((tk*8 + tn)*64 + lane)*8);
        c[tn] = __builtin_amdgcn_mfma_f32_16x16x32_bf16(a, b, c[tn], 0, 0, 0);
      }
    }
    #pragma unroll
    for (int tn = 0; tn < 8; tn++){
      int n = tn*16 + ln;
      #pragma unroll
      for (int r = 0; r < 4; r++)
        sacc[tn][r] += tileF[q*4 + r][n] * c[tn][r];
    }
  }
  float anew[8][4];
  #pragma unroll
  for (int tn = 0; tn < 8; tn++){
    int n = tn*16 + ln;
    #pragma unroll
    for (int r = 0; r < 4; r++){
      size_t idx = (size_t)(n0 + q*4 + r)*NF + n;
      float v = atom[idx] + sacc[tn][r];
      atom[idx] = v;
      anew[tn][r] = v;
    }
  }
  if (!do_mlp) return;

  // ---- phase 2: h(l+1) ----
  #pragma unroll
  for (int tn = 0; tn < 8; tn++){
    int n = tn*16 + ln;
    #pragma unroll
    for (int r = 0; r < 4; r++) tile[q*4 + r][n] = f2b(anew[tn][r]);
  }
  floatx4 c1[8];
  #pragma unroll
  for (int tn = 0; tn < 8; tn++) c1[tn] = (floatx4){0,0,0,0};
  #pragma unroll
  for (int tk = 0; tk < 4; tk++){
    short8 a = *(const short8*)&tile[ln][tk*32 + q*8];
    #pragma unroll
    for (int tn = 0; tn < 8; tn++){
      short8 b = *(const short8*)(w1sw + (size_t)((tk*8 + tn)*64 + lane)*8);
      c1[tn] = __builtin_amdgcn_mfma_f32_16x16x32_bf16(a, b, c1[tn], 0, 0, 0);
    }
  }
  #pragma unroll
  for (int tn = 0; tn < 8; tn++){
    int n = tn*16 + ln;
    float bias = b1[n];
    #pragma unroll
    for (int r = 0; r < 4; r++)
      tile[q*4 + r][n] = f2b(fast_silu(c1[tn][r] + bias));
  }
  floatx4 c2[8];
  #pragma unroll
  for (int tn = 0; tn < 8; tn++) c2[tn] = (floatx4){0,0,0,0};
  #pragma unroll
  for (int tk = 0; tk < 4; tk++){
    short8 a = *(const short8*)&tile[ln][tk*32 + q*8];
    #pragma unroll
    for (int tn = 0; tn < 8; tn++){
      short8 b = *(const short8*)(w2sw + (size_t)((tk*8 + tn)*64 + lane)*8);
      c2[tn] = __builtin_amdgcn_mfma_f32_16x16x32_bf16(a, b, c2[tn], 0, 0, 0);
    }
  }
  float b2n[8];
  #pragma unroll
  for (int tn = 0; tn < 8; tn++) b2n[tn] = b2[tn*16 + ln];
  #pragma unroll
  for (int tn = 0; tn < 4; tn++){
    #pragma unroll
    for (int r = 0; r < 4; r++){
      float vl = c2[tn][r]   + b2n[tn];
      float vh = c2[tn+4][r] + b2n[tn+4];
      hb[(size_t)(n0 + q*4 + r)*64 + tn*16 + ln] = packbf(vl, vh);
    }
  }
}

// ---------------- write out ----------------
__global__ __launch_bounds__(256) void k_writeout(const float* __restrict__ atom,
                                                  const float* __restrict__ force,
                                                  void* __restrict__ out,
                                                  const int* __restrict__ flag){
  int idx = blockIdx.x * 256 + threadIdx.x;
  const int na = NN * NF;
  const int tot = na + NN * 3 * NF;
  if (idx >= tot) return;
  float v = (idx < na) ? atom[idx] : force[idx - na];
  if (*flag) ((__hip_bfloat16*)out)[idx] = __float2bfloat16(v);
  else       ((float*)out)[idx] = v;
}

extern "C" void kernel_launch(void* const* d_in, const int* in_sizes, int n_in,
                              void* d_out, int out_size, void* d_ws, size_t ws_size,
                              hipStream_t stream){
  const int* z    = (const int*)d_in[0];
  const void* pos = d_in[1];
  // d_in[2] cell, d_in[3] batch: numerically dead (sym == I)
  const int* ei   = (const int*)d_in[4];
  const void* emb   = d_in[5];
  const void* mnpW1 = d_in[6];
  const void* mnpb1 = d_in[7];
  const void* mnpW2 = d_in[8];
  const void* mnpb2 = d_in[9];
  const void* meW   = d_in[10];
  const void* em1W1 = d_in[11];
  const void* em1W2 = d_in[12];
  const void* em2W1 = d_in[13];
  const void* em2W2 = d_in[14];
  const void* euW   = d_in[15];

  float* base  = (float*)d_ws;
  int*   flag  = (int*)d_ws;                  // 4 floats reserved
  float* atom   = base + 4;                   // NN*NF
  float* force  = atom   + NN*NF;             // NN*3*NF
  float* fdelta = force  + (size_t)NN*3*NF;   // NN*3*NF
  u32*   forceb = (u32*)(fdelta + (size_t)NN*3*NF);  // NN*3*64
  int*   count  = (int*)(forceb + (size_t)NN*3*64);  // NN
  // single memset zeroes force, fdelta, forceb, count (contiguous)
  float* ds    = (float*)(count + NN);
  float* dirs  = ds + NE;
  float* posf  = dirs + 3*NE;
  float* embf  = posf + NN*3;
  float* b1f   = embf + 119*NF;               // 3*NF
  float* b2f_  = b1f + 3*NF;                  // 3*NF
  u32*   hb    = (u32*)(b2f_ + 3*NF);         // NN*64
  u16*   mesw  = (u16*)(hb + (size_t)NN*64);  // 3*4096
  u16*   w11sw = mesw  + 3*4096;
  u16*   w12sw = w11sw + 3*16384;
  u16*   w21sw = w12sw + 3*16384;
  u16*   w22sw = w21sw + 3*16384;
  u16*   w1sw  = w22sw + 3*16384;
  u16*   w2sw  = w1sw  + 3*16384;
  u16*   eusw  = w2sw  + 3*16384;
  int* rowptr  = (int*)(eusw + 3*16384);      // NN+1
  int* cursor  = rowptr + NN + 1;
  int* iis     = cursor + NN;                 // NE
  int* jjs     = iis + NE;

  k_detect<<<1, 256, 0, stream>>>(meW, 3*NB*NF, flag);

  // zero force + fdelta + forceb + count in one shot
  hipMemsetAsync(force, 0, ((size_t)NN*3*NF*2 + (size_t)NN*3*64 + NN)*4, stream);

  PrepArgs pa;
  pa.csrc[0]=pos;   pa.cdst[0]=posf; pa.cn[0]=NN*3;
  pa.csrc[1]=emb;   pa.cdst[1]=embf; pa.cn[1]=119*NF;
  pa.csrc[2]=mnpb1; pa.cdst[2]=b1f;  pa.cn[2]=3*NF;
  pa.csrc[3]=mnpb2; pa.cdst[3]=b2f_; pa.cn[3]=3*NF;
  pa.ssrc[0]=em1W1; pa.sdst[0]=w11sw;
  pa.ssrc[1]=em1W2; pa.sdst[1]=w12sw;
  pa.ssrc[2]=em2W1; pa.sdst[2]=w21sw;
  pa.ssrc[3]=em2W2; pa.sdst[3]=w22sw;
  pa.ssrc[4]=mnpW1; pa.sdst[4]=w1sw;
  pa.ssrc[5]=mnpW2; pa.sdst[5]=w2sw;
  pa.ssrc[6]=euW;   pa.sdst[6]=eusw;
  pa.mesrc=meW;     pa.medst=mesw;
  k_prep<<<dim3(192,12), 256, 0, stream>>>(pa, flag);

  k_hist         <<<(NE+255)/256, 256, 0, stream>>>(ei, count);
  k_scan         <<<1, 256, 0, stream>>>(count, rowptr, cursor);
  k_scatter_embed<<<(NE+255)/256, 256, 0, stream>>>(ei, cursor, posf, iis, jjs, ds, dirs);

  // layer 0 MLP with fused atom init
  k_mlp0<<<NN/16, 64, 0, stream>>>(z, embf, atom, w1sw, b1f, w2sw, b2f_, hb);
  for (int l = 0; l < 3; l++){
    k_edge_mfma<<<NE/16, 64, 0, stream>>>(iis, jjs, ds, dirs, hb,
        mesw  + (size_t)l*4096,
        w11sw + (size_t)l*16384, w12sw + (size_t)l*16384,
        w21sw + (size_t)l*16384, w22sw + (size_t)l*16384,
        atom, forceb, fdelta);
    int nl = l + 1;
    k_node_fused<<<NN/16, 64, 0, stream>>>(force, fdelta,
        eusw + (size_t)l*16384, atom, forceb,
        w1sw + (size_t)(nl%3)*16384, b1f + (size_t)(nl%3)*NF,
        w2sw + (size_t)(nl%3)*16384, b2f_ + (size_t)(nl%3)*NF,
        hb, (l < 2) ? 1 : 0);
  }

  k_writeout<<<(NN*NF + NN*3*NF + 255)/256, 256, 0, stream>>>(atom, force, d_out, flag);
}